// Round 9
// baseline (712.188 us; speedup 1.0000x reference)
//
#include <hip/hip_runtime.h>
#include <cstddef>

static constexpr int kN = 4096;
static constexpr int kF = 512;
static constexpr int kH = 256;
static constexpr float kClamp = 1e-6f;

using bf16x8 = __attribute__((ext_vector_type(8))) __bf16;
using f32x4 = __attribute__((ext_vector_type(4))) float;
using ushort8 = __attribute__((ext_vector_type(8))) unsigned short;
using ushort4v = __attribute__((ext_vector_type(4))) unsigned short;

static constexpr size_t PLANE_XF = (size_t)kN * kF;      // 2.1M
static constexpr size_t PLANE_NN = (size_t)kN * kN;      // 16.8M
static constexpr size_t PLANE_W = (size_t)512 * 512;
static constexpr size_t PLANE_W1 = (size_t)256 * 512;
static constexpr size_t PLANE_V0 = (size_t)1024 * kN;
static constexpr size_t PLANE_H = (size_t)kN * 1024;
static constexpr size_t PLANE_V1 = (size_t)512 * kN;

__device__ __forceinline__ unsigned short f2bf(float x) {
  unsigned int u = __float_as_uint(x);
  u += 0x7fffu + ((u >> 16) & 1u);
  return (unsigned short)(u >> 16);
}
__device__ __forceinline__ float bf2f(unsigned short h) {
  return __uint_as_float(((unsigned int)h) << 16);
}
__device__ __forceinline__ void split3(float x, unsigned short& h,
                                       unsigned short& m, unsigned short& l) {
  h = f2bf(x);
  const float r1 = x - bf2f(h);
  m = f2bf(r1);
  l = f2bf(r1 - bf2f(m));
}
__device__ __forceinline__ void split2(float x, unsigned short& h,
                                       unsigned short& m) {
  h = f2bf(x);
  m = f2bf(x - bf2f(h));
}
__device__ __forceinline__ void split2x4(const float4 v, ushort4v& h4,
                                         ushort4v& m4) {
  unsigned short h, m;
  split2(v.x, h, m); h4.x = h; m4.x = m;
  split2(v.y, h, m); h4.y = h; m4.y = m;
  split2(v.z, h, m); h4.z = h; m4.z = m;
  split2(v.w, h, m); h4.w = h; m4.w = m;
}

__device__ __forceinline__ bf16x8 ldfrag(const unsigned short* p) {
  ushort8 r = *(const ushort8*)p;
  return __builtin_bit_cast(bf16x8, r);
}
__device__ __forceinline__ f32x4 mfma16(bf16x8 a, bf16x8 b, f32x4 c) {
  return __builtin_amdgcn_mfma_f32_16x16x32_bf16(a, b, c, 0, 0, 0);
}
// 6-product (split3): rel err ~2^-26
__device__ __forceinline__ f32x4 mfma_split6(const bf16x8* a3, const bf16x8* b3,
                                             f32x4 acc) {
  acc = mfma16(a3[2], b3[0], acc);
  acc = mfma16(a3[0], b3[2], acc);
  acc = mfma16(a3[1], b3[1], acc);
  acc = mfma16(a3[1], b3[0], acc);
  acc = mfma16(a3[0], b3[1], acc);
  acc = mfma16(a3[0], b3[0], acc);
  return acc;
}

__device__ __forceinline__ void tri_map(int b, int& bi, int& bj) {
  int x = (int)((sqrtf(8.0f * (float)b + 1.0f) - 1.0f) * 0.5f);
  while ((x + 1) * (x + 2) / 2 <= b) ++x;
  while (x * (x + 1) / 2 > b) --x;
  bi = x;
  bj = b - x * (x + 1) / 2;
}

__device__ __forceinline__ float block_reduce_sum(float v, float* sbuf) {
  const int tid = threadIdx.x;
  sbuf[tid] = v;
  __syncthreads();
#pragma unroll
  for (int s = 128; s > 0; s >>= 1) {
    if (tid < s) sbuf[tid] += sbuf[tid + s];
    __syncthreads();
  }
  const float r = sbuf[0];
  __syncthreads();
  return r;
}

// ============ prep: transpose+split weights ============
__global__ __launch_bounds__(256) void prep_w(
    const float* s0, const float* s1, const float* s2, const float* s3,
    const float* s4, const float* s5, unsigned short* d0, unsigned short* d1,
    unsigned short* d2, unsigned short* d3, unsigned short* d4,
    unsigned short* d5) {
  const int seg = blockIdx.y;
  const float* src;
  unsigned short* dst;
  int N;
  bool tri;
  switch (seg) {
    case 0: src = s0; dst = d0; N = 512; tri = true; break;
    case 1: src = s1; dst = d1; N = 512; tri = true; break;
    case 2: src = s2; dst = d2; N = 512; tri = false; break;
    case 3: src = s3; dst = d3; N = 512; tri = false; break;
    case 4: src = s4; dst = d4; N = 256; tri = false; break;
    default: src = s5; dst = d5; N = 256; tri = false; break;
  }
  const int id = blockIdx.x * 256 + threadIdx.x;
  if (id >= 512 * N) return;
  const int k = id & 511;
  const int n = id >> 9;
  const float v = src[(size_t)k * N + n];
  const size_t base = (size_t)n * 512 + k;
  const size_t plane = (size_t)512 * N;
  if (tri) {
    unsigned short h, m, l;
    split3(v, h, m, l);
    dst[base] = h;
    dst[plane + base] = m;
    dst[2 * plane + base] = l;
  } else {
    unsigned short h, m;
    split2(v, h, m);
    dst[base] = h;
    dst[plane + base] = m;
  }
}

// ============ split x into 3 planes ============
__global__ __launch_bounds__(256) void split_x(const float* __restrict__ x,
                                               unsigned short* __restrict__ x3) {
  const size_t id = (size_t)blockIdx.x * 256 + threadIdx.x;
  unsigned short h, m, l;
  split3(x[id], h, m, l);
  x3[id] = h;
  x3[PLANE_XF + id] = m;
  x3[2 * PLANE_XF + id] = l;
}

// ============ GEMM-1 (split3, 6-product): x@Wm|Ws -> XMf|XSf (f32) ============
__global__ __launch_bounds__(256) void gemm_x(
    const unsigned short* __restrict__ A3, const unsigned short* __restrict__ B30,
    const unsigned short* __restrict__ B31, float* __restrict__ C0,
    float* __restrict__ C1, const float* __restrict__ bias0,
    const float* __restrict__ bias1) {
  constexpr int BM = 128, BN = 64, K = 512;
  __shared__ __align__(16) unsigned short Asl[3][BM][40];
  __shared__ __align__(16) unsigned short Bsl[3][BN][40];
  const int tid = threadIdx.x;
  const int lane = tid & 63;
  const int wave = tid >> 6;
  const int wm = wave >> 1, wn = wave & 1;
  const int m0 = blockIdx.y * BM;
  const int n0 = blockIdx.x * BN;
  const bool str1 = (n0 >= 512);
  const int nloc = str1 ? (n0 - 512) : n0;
  const unsigned short* Bb = str1 ? B31 : B30;
  const float* bias = str1 ? bias1 : bias0;
  float* C = str1 ? C1 : C0;
  const int rl = lane & 15;
  const int kq = (lane >> 4) * 8;
  const int q = lane >> 4;

  f32x4 acc[4][2];
#pragma unroll
  for (int i = 0; i < 4; ++i)
#pragma unroll
    for (int j = 0; j < 2; ++j) acc[i][j] = (f32x4){0.f, 0.f, 0.f, 0.f};

  for (int k0 = 0; k0 < K; k0 += 32) {
#pragma unroll
    for (int it = 0; it < 6; ++it) {
      const int c = tid + it * 256;
      const int plane = c / (BM * 4);
      const int rem = c % (BM * 4);
      const int row = rem >> 2;
      const int kc = (rem & 3) * 8;
      const ushort8 v = *(const ushort8*)(&A3[(size_t)plane * PLANE_XF +
                                              (size_t)(m0 + row) * K + k0 + kc]);
      *(ushort8*)(&Asl[plane][row][kc]) = v;
    }
#pragma unroll
    for (int it = 0; it < 3; ++it) {
      const int c = tid + it * 256;
      const int plane = c / (BN * 4);
      const int rem = c % (BN * 4);
      const int row = rem >> 2;
      const int kc = (rem & 3) * 8;
      const ushort8 v = *(const ushort8*)(&Bb[(size_t)plane * PLANE_W +
                                              (size_t)(nloc + row) * K + k0 + kc]);
      *(ushort8*)(&Bsl[plane][row][kc]) = v;
    }
    __syncthreads();
    bf16x8 af[4][3], bfr[2][3];
#pragma unroll
    for (int mt = 0; mt < 4; ++mt)
#pragma unroll
      for (int t = 0; t < 3; ++t)
        af[mt][t] = ldfrag(&Asl[t][wm * 64 + mt * 16 + rl][kq]);
#pragma unroll
    for (int nt = 0; nt < 2; ++nt)
#pragma unroll
      for (int t = 0; t < 3; ++t)
        bfr[nt][t] = ldfrag(&Bsl[t][wn * 32 + nt * 16 + rl][kq]);
#pragma unroll
    for (int mt = 0; mt < 4; ++mt)
#pragma unroll
      for (int nt = 0; nt < 2; ++nt)
        acc[mt][nt] = mfma_split6(af[mt], bfr[nt], acc[mt][nt]);
    __syncthreads();
  }
#pragma unroll
  for (int mt = 0; mt < 4; ++mt)
#pragma unroll
    for (int nt = 0; nt < 2; ++nt) {
      const int col = nloc + wn * 32 + nt * 16 + rl;
      const int row0 = m0 + wm * 64 + mt * 16 + q * 4;
      const float bv = bias[col];
#pragma unroll
      for (int r = 0; r < 4; ++r)
        C[(size_t)(row0 + r) * 512 + col] = acc[mt][nt][r] + bv;
    }
}

// ============ split2 3-product GEMM, CT-split2 output (small GEMMs) ============
template <int BM, int BN>
__global__ __launch_bounds__(256) void gemm2ct(
    const unsigned short* __restrict__ A0, const unsigned short* __restrict__ A1,
    int lda, size_t planeA, const unsigned short* __restrict__ B0,
    const unsigned short* __restrict__ B1, int ldb, size_t planeB,
    unsigned short* __restrict__ Cs0, unsigned short* __restrict__ Cs1, int ldc,
    size_t planeC, int N1, int K, const float* __restrict__ rowScale) {
  __shared__ __align__(16) unsigned short Asl[2][BM][40];
  __shared__ __align__(16) unsigned short Bsl[2][BN][40];
  const int tid = threadIdx.x;
  const int lane = tid & 63;
  const int wave = tid >> 6;
  const int wm = wave >> 1, wn = wave & 1;
  const int m0 = blockIdx.y * BM;
  const int n0 = blockIdx.x * BN;
  const bool str1 = (n0 >= N1);
  const int nloc = str1 ? (n0 - N1) : n0;
  const unsigned short* Ab = str1 ? A1 : A0;
  const unsigned short* Bb = str1 ? B1 : B0;
  const int rl = lane & 15;
  const int kq = (lane >> 4) * 8;
  const int q = lane >> 4;
  constexpr int MT = BM / 32;
  constexpr int NT = BN / 32;

  f32x4 acc[MT][NT];
#pragma unroll
  for (int i = 0; i < MT; ++i)
#pragma unroll
    for (int j = 0; j < NT; ++j) acc[i][j] = (f32x4){0.f, 0.f, 0.f, 0.f};

  for (int k0 = 0; k0 < K; k0 += 32) {
    constexpr int AIT = (2 * BM * 4) / 256;
#pragma unroll
    for (int it = 0; it < AIT; ++it) {
      const int c = tid + it * 256;
      const int plane = c / (BM * 4);
      const int rem = c % (BM * 4);
      const int row = rem >> 2;
      const int kc = (rem & 3) * 8;
      const ushort8 v = *(const ushort8*)(&Ab[(size_t)plane * planeA +
                                              (size_t)(m0 + row) * lda + k0 + kc]);
      *(ushort8*)(&Asl[plane][row][kc]) = v;
    }
    constexpr int BIT = (2 * BN * 4) / 256;
#pragma unroll
    for (int it = 0; it < BIT; ++it) {
      const int c = tid + it * 256;
      const int plane = c / (BN * 4);
      const int rem = c % (BN * 4);
      const int row = rem >> 2;
      const int kc = (rem & 3) * 8;
      const ushort8 v = *(const ushort8*)(&Bb[(size_t)plane * planeB +
                                              (size_t)(nloc + row) * ldb + k0 + kc]);
      *(ushort8*)(&Bsl[plane][row][kc]) = v;
    }
    __syncthreads();
    bf16x8 af[MT][2];
#pragma unroll
    for (int mt = 0; mt < MT; ++mt)
#pragma unroll
      for (int t = 0; t < 2; ++t)
        af[mt][t] = ldfrag(&Asl[t][wm * (BM / 2) + mt * 16 + rl][kq]);
#pragma unroll
    for (int nt = 0; nt < NT; ++nt) {
      const bf16x8 b0 = ldfrag(&Bsl[0][wn * (BN / 2) + nt * 16 + rl][kq]);
      const bf16x8 b1 = ldfrag(&Bsl[1][wn * (BN / 2) + nt * 16 + rl][kq]);
#pragma unroll
      for (int mt = 0; mt < MT; ++mt) {
        acc[mt][nt] = mfma16(af[mt][1], b0, acc[mt][nt]);
        acc[mt][nt] = mfma16(af[mt][0], b1, acc[mt][nt]);
        acc[mt][nt] = mfma16(af[mt][0], b0, acc[mt][nt]);
      }
    }
    __syncthreads();
  }

#pragma unroll
  for (int mt = 0; mt < MT; ++mt) {
#pragma unroll
    for (int nt = 0; nt < NT; ++nt) {
      const int colL = nloc + wn * (BN / 2) + nt * 16 + rl;
      const int row0 = m0 + wm * (BM / 2) + mt * 16 + q * 4;
      float4 v4;
      float* vp = &v4.x;
#pragma unroll
      for (int r = 0; r < 4; ++r) {
        float v = acc[mt][nt][r];
        if (rowScale) v *= rowScale[row0 + r];
        vp[r] = v;
      }
      unsigned short* C = str1 ? Cs1 : Cs0;
      ushort4v h4, m4;
      split2x4(v4, h4, m4);
      const size_t base = (size_t)colL * ldc + row0;
      *(ushort4v*)(&C[base]) = h4;
      *(ushort4v*)(&C[planeC + base]) = m4;
    }
  }
}

// ============ split2 3-product GEMM, split-K partials, XCD-swizzled ============
template <int BM, int BN, int GX, int GYP, int GZ>
__global__ __launch_bounds__(256) void gemm2k(
    const unsigned short* __restrict__ A, int lda, size_t planeA,
    const unsigned short* __restrict__ B, int ldb, size_t planeB,
    float* __restrict__ Cp, int ldc, int Mtot, int Ksl) {
  __shared__ __align__(16) unsigned short Asl[2][BM][40];
  __shared__ __align__(16) unsigned short Bsl[2][BN][40];
  const int lin = blockIdx.x;
  const int xcd = lin & 7;
  const int s = lin >> 3;
  constexpr int per = GX * GYP;
  const int z = s / per;
  const int r = s - z * per;
  const int bx = r % GX;
  const int by = xcd * GYP + r / GX;
  const int m0 = by * BM;
  const int n0 = bx * BN;
  const int kOff = z * Ksl;

  const int tid = threadIdx.x;
  const int lane = tid & 63;
  const int wave = tid >> 6;
  const int wm = wave >> 1, wn = wave & 1;
  const int rl = lane & 15;
  const int kq = (lane >> 4) * 8;
  const int q = lane >> 4;
  constexpr int MT = BM / 32;
  constexpr int NT = BN / 32;

  f32x4 acc[MT][NT];
#pragma unroll
  for (int i = 0; i < MT; ++i)
#pragma unroll
    for (int j = 0; j < NT; ++j) acc[i][j] = (f32x4){0.f, 0.f, 0.f, 0.f};

  for (int k0 = 0; k0 < Ksl; k0 += 32) {
    constexpr int AIT = (2 * BM * 4) / 256;
#pragma unroll
    for (int it = 0; it < AIT; ++it) {
      const int c = tid + it * 256;
      const int plane = c / (BM * 4);
      const int rem = c % (BM * 4);
      const int row = rem >> 2;
      const int kc = (rem & 3) * 8;
      const ushort8 v = *(const ushort8*)(&A[(size_t)plane * planeA +
                                             (size_t)(m0 + row) * lda + kOff +
                                             k0 + kc]);
      *(ushort8*)(&Asl[plane][row][kc]) = v;
    }
    constexpr int BIT = (2 * BN * 4) / 256;
#pragma unroll
    for (int it = 0; it < BIT; ++it) {
      const int c = tid + it * 256;
      const int plane = c / (BN * 4);
      const int rem = c % (BN * 4);
      const int row = rem >> 2;
      const int kc = (rem & 3) * 8;
      const ushort8 v = *(const ushort8*)(&B[(size_t)plane * planeB +
                                             (size_t)(n0 + row) * ldb + kOff +
                                             k0 + kc]);
      *(ushort8*)(&Bsl[plane][row][kc]) = v;
    }
    __syncthreads();
    bf16x8 af[MT][2];
#pragma unroll
    for (int mt = 0; mt < MT; ++mt)
#pragma unroll
      for (int t = 0; t < 2; ++t)
        af[mt][t] = ldfrag(&Asl[t][wm * (BM / 2) + mt * 16 + rl][kq]);
#pragma unroll
    for (int nt = 0; nt < NT; ++nt) {
      const bf16x8 b0 = ldfrag(&Bsl[0][wn * (BN / 2) + nt * 16 + rl][kq]);
      const bf16x8 b1 = ldfrag(&Bsl[1][wn * (BN / 2) + nt * 16 + rl][kq]);
#pragma unroll
      for (int mt = 0; mt < MT; ++mt) {
        acc[mt][nt] = mfma16(af[mt][1], b0, acc[mt][nt]);
        acc[mt][nt] = mfma16(af[mt][0], b1, acc[mt][nt]);
        acc[mt][nt] = mfma16(af[mt][0], b0, acc[mt][nt]);
      }
    }
    __syncthreads();
  }

  const size_t zoff = (size_t)z * (size_t)Mtot * (size_t)ldc;
#pragma unroll
  for (int mt = 0; mt < MT; ++mt) {
#pragma unroll
    for (int nt = 0; nt < NT; ++nt) {
      const int colL = n0 + wn * (BN / 2) + nt * 16 + rl;
      const int row0 = m0 + wm * (BM / 2) + mt * 16 + q * 4;
#pragma unroll
      for (int r = 0; r < 4; ++r)
        Cp[zoff + (size_t)(row0 + r) * ldc + colL] = acc[mt][nt][r];
    }
  }
}

// ============ row stats: XMf/XSf f32 -> M2/CS2/XM2/XS2 planes ============
__global__ __launch_bounds__(256) void row_stats(
    const float* __restrict__ XMf, const float* __restrict__ XSf,
    unsigned short* __restrict__ M2, unsigned short* __restrict__ CS2,
    unsigned short* __restrict__ XM2, unsigned short* __restrict__ XS2,
    float* __restrict__ sq, float* __restrict__ csum) {
  __shared__ float sbuf[256];
  const int i = blockIdx.x;
  const int tid = threadIdx.x;
  const size_t base = (size_t)i * kF;
  const size_t i0 = base + tid, i1 = base + tid + 256;
  const float x0 = XMf[i0], x1 = XMf[i1];
  {
    unsigned short h, m;
    split2(x0, h, m);
    XM2[i0] = h; XM2[PLANE_XF + i0] = m;
    split2(x1, h, m);
    XM2[i1] = h; XM2[PLANE_XF + i1] = m;
  }
  const float nrm = block_reduce_sum(x0 * x0 + x1 * x1, sbuf);
  const float inv = 1.0f / fmaxf(sqrtf(nrm), 1e-12f);
  const float m0 = x0 * inv, m1 = x1 * inv;
  {
    unsigned short h, m;
    split2(m0, h, m);
    M2[i0] = h; M2[PLANE_XF + i0] = m;
    split2(m1, h, m);
    M2[i1] = h; M2[PLANE_XF + i1] = m;
  }
  const float s2 = block_reduce_sum(m0 * m0 + m1 * m1, sbuf);
  if (tid == 0) sq[i] = s2;

  const float y0 = XSf[i0], y1 = XSf[i1];
  {
    unsigned short h, m;
    split2(y0, h, m);
    XS2[i0] = h; XS2[PLANE_XF + i0] = m;
    split2(y1, h, m);
    XS2[i1] = h; XS2[PLANE_XF + i1] = m;
  }
  const float e0 = expf(y0), e1 = expf(y1);
  const float nrm2 = block_reduce_sum(e0 * e0 + e1 * e1, sbuf);
  const float inv2 = 1.0f / fmaxf(sqrtf(nrm2), 1e-12f);
  const float c0 = e0 * inv2, c1 = e1 * inv2;
  const float sc = block_reduce_sum(c0 + c1, sbuf);
  if (tid == 0) csum[i] = sc;
  {
    unsigned short h, m;
    split2(sqrtf(c0), h, m);
    CS2[i0] = h; CS2[PLANE_XF + i0] = m;
    split2(sqrtf(c1), h, m);
    CS2[i1] = h; CS2[PLANE_XF + i1] = m;
  }
}

// ============ symmetric dual NT-GEMM, 128x128 tiles, 3-prod split2 ============
// Also emits per-tile row/col sum-of-squares partials (rsqp[32][4096]) so the
// separate row_invnorm pass over WSR is not needed.
__global__ __launch_bounds__(256, 2) void ws_mfma2(
    const unsigned short* __restrict__ M2, const unsigned short* __restrict__ CS2,
    const float* __restrict__ sq, const float* __restrict__ csum,
    float* __restrict__ WSR, float* __restrict__ rsqp) {
  __shared__ __align__(16) unsigned short S[4][2][128][40];  // 80 KB
  int bi, bj;
  tri_map(blockIdx.x, bi, bj);  // 32x32 tile grid, bi >= bj
  const int i0 = bi * 128, j0 = bj * 128;
  const int tid = threadIdx.x;
  const int lane = tid & 63;
  const int wave = tid >> 6;
  const int wm = wave >> 1, wn = wave & 1;
  const int rl = lane & 15;
  const int kq = (lane >> 4) * 8;
  const int q = lane >> 4;

  f32x4 aM[4][4], aC[4][4];
#pragma unroll
  for (int i = 0; i < 4; ++i)
#pragma unroll
    for (int j = 0; j < 4; ++j) {
      aM[i][j] = (f32x4){0.f, 0.f, 0.f, 0.f};
      aC[i][j] = (f32x4){0.f, 0.f, 0.f, 0.f};
    }

  for (int k0 = 0; k0 < kF; k0 += 32) {
    // stage 4 ops x 2 planes x 128 rows x 32 k  (4096 ushort8 slots)
#pragma unroll
    for (int it = 0; it < 16; ++it) {
      const int c = tid + it * 256;
      const int op = c >> 10;
      const int rem = c & 1023;
      const int plane = rem >> 9;
      const int r2 = rem & 511;
      const int row = r2 >> 2;
      const int kc = (r2 & 3) * 8;
      const unsigned short* mat = (op & 1) ? CS2 : M2;
      const int rowoff = (op < 2) ? i0 : j0;
      const ushort8 v = *(const ushort8*)(&mat[(size_t)plane * PLANE_XF +
                                               (size_t)(rowoff + row) * kF + k0 +
                                               kc]);
      *(ushort8*)(&S[op][plane][row][kc]) = v;
    }
    __syncthreads();
    {
      bf16x8 a_[4][2], b_[4][2];
#pragma unroll
      for (int mt = 0; mt < 4; ++mt)
#pragma unroll
        for (int t = 0; t < 2; ++t)
          a_[mt][t] = ldfrag(&S[0][t][wm * 64 + mt * 16 + rl][kq]);
#pragma unroll
      for (int nt = 0; nt < 4; ++nt)
#pragma unroll
        for (int t = 0; t < 2; ++t)
          b_[nt][t] = ldfrag(&S[2][t][wn * 64 + nt * 16 + rl][kq]);
#pragma unroll
      for (int mt = 0; mt < 4; ++mt)
#pragma unroll
        for (int nt = 0; nt < 4; ++nt) {
          aM[mt][nt] = mfma16(a_[mt][1], b_[nt][0], aM[mt][nt]);
          aM[mt][nt] = mfma16(a_[mt][0], b_[nt][1], aM[mt][nt]);
          aM[mt][nt] = mfma16(a_[mt][0], b_[nt][0], aM[mt][nt]);
        }
    }
    {
      bf16x8 a_[4][2], b_[4][2];
#pragma unroll
      for (int mt = 0; mt < 4; ++mt)
#pragma unroll
        for (int t = 0; t < 2; ++t)
          a_[mt][t] = ldfrag(&S[1][t][wm * 64 + mt * 16 + rl][kq]);
#pragma unroll
      for (int nt = 0; nt < 4; ++nt)
#pragma unroll
        for (int t = 0; t < 2; ++t)
          b_[nt][t] = ldfrag(&S[3][t][wn * 64 + nt * 16 + rl][kq]);
#pragma unroll
      for (int mt = 0; mt < 4; ++mt)
#pragma unroll
        for (int nt = 0; nt < 4; ++nt) {
          aC[mt][nt] = mfma16(a_[mt][1], b_[nt][0], aC[mt][nt]);
          aC[mt][nt] = mfma16(a_[mt][0], b_[nt][1], aC[mt][nt]);
          aC[mt][nt] = mfma16(a_[mt][0], b_[nt][0], aC[mt][nt]);
        }
    }
    __syncthreads();
  }

  // epilogue: reuse S memory for row/col sum-of-squares reduction
  float* rs_ = (float*)&S[0][0][0][0];  // [128] row partials (direct tile)
  float* cs_ = rs_ + 128;               // [128] col partials (mirror rows)
  if (tid < 256) rs_[tid] = 0.f;        // zero both arrays
  __syncthreads();

  float rowacc[4][4];
  float colacc[4];
#pragma unroll
  for (int i = 0; i < 4; ++i) {
    colacc[i] = 0.f;
#pragma unroll
    for (int j = 0; j < 4; ++j) rowacc[i][j] = 0.f;
  }

#pragma unroll
  for (int mt = 0; mt < 4; ++mt) {
#pragma unroll
    for (int nt = 0; nt < 4; ++nt) {
      const int j = j0 + wn * 64 + nt * 16 + rl;
      const int ib = i0 + wm * 64 + mt * 16 + q * 4;
      const float sqj = sq[j], csj = csum[j];
      float4 vv;
      float* vp = &vv.x;
#pragma unroll
      for (int r = 0; r < 4; ++r) {
        const int i = ib + r;
        const float d2 = fmaxf(sq[i] + sqj - 2.0f * aM[mt][nt][r], 0.0f);
        const float res = d2 + csum[i] + csj - 2.0f * aC[mt][nt][r];
        const float v = expf(-res);
        vp[r] = v;
        WSR[(size_t)i * kN + j] = v;
        rowacc[mt][r] += v * v;
        colacc[nt] += v * v;
      }
      if (bi != bj) *(float4*)(&WSR[(size_t)j * kN + ib]) = vv;
    }
  }
#pragma unroll
  for (int mt = 0; mt < 4; ++mt)
#pragma unroll
    for (int r = 0; r < 4; ++r)
      atomicAdd(&rs_[wm * 64 + mt * 16 + q * 4 + r], rowacc[mt][r]);
#pragma unroll
  for (int nt = 0; nt < 4; ++nt)
    atomicAdd(&cs_[wn * 64 + nt * 16 + rl], colacc[nt]);
  __syncthreads();
  if (tid < 128) {
    rsqp[(size_t)bj * kN + i0 + tid] = rs_[tid];
    if (bi != bj) rsqp[(size_t)bi * kN + j0 + tid] = cs_[tid];
  }
}

// ============ invn from rsqp slabs ============
__global__ __launch_bounds__(256) void invn_from_rsqp(
    const float* __restrict__ rsqp, float* __restrict__ invn) {
  const int i = blockIdx.x * 256 + threadIdx.x;
  float s = 0.0f;
#pragma unroll
  for (int c = 0; c < 32; ++c) s += rsqp[(size_t)c * kN + i];
  invn[i] = 1.0f / fmaxf(sqrtf(s), 1e-12f);
}

// ============ adjacency transform + transposed 2-plane split + deg ============
__device__ __forceinline__ float adj_val(float w, float inv, float nev, float ev,
                                         float b, float d, bool diag) {
  float t = (1.0f - b) * (w * inv) + b * nev;
  t = fminf(fmaxf(t, kClamp), 1.0f - kClamp);
  float L = logf(t / (1.0f - t));
  const float e = fminf(fmaxf(ev, kClamp), 1.0f - kClamp);
  L += logf(e / (1.0f - e));
  const float s = 1.0f / (1.0f + expf(-L));
  float v = (s > d) ? s : 0.0f;
  if (diag) v = (v > 0.0f) ? v : 1.0f;
  return v;
}

__global__ __launch_bounds__(256) void adj_transpose(
    const float* __restrict__ WSR, const float* __restrict__ invn,
    const float* __restrict__ ne, const float* __restrict__ epsm,
    const float* __restrict__ beta_p, const float* __restrict__ delta_p,
    unsigned short* __restrict__ Adj2, float* __restrict__ degp) {
  __shared__ float T0[64][65];
  __shared__ float T1[64][65];
  const float b = beta_p[0];
  const float d = delta_p[0];
  int bi, bj;
  tri_map(blockIdx.x, bi, bj);
  const int i0 = bi * 64, j0 = bj * 64;
  const int tid = threadIdx.x;
  const int rlq = tid >> 4;
  const int cq = (tid & 15) * 4;
#pragma unroll
  for (int p = 0; p < 4; ++p) {
    const int ii = p * 16 + rlq;
    {
      const size_t off = (size_t)(i0 + ii) * kN + j0 + cq;
      const float4 w4 = *(const float4*)(&WSR[off]);
      const float4 n4 = *(const float4*)(&ne[off]);
      const float4 e4 = *(const float4*)(&epsm[off]);
      const float inv = invn[i0 + ii];
      const float wv[4] = {w4.x, w4.y, w4.z, w4.w};
      const float nv[4] = {n4.x, n4.y, n4.z, n4.w};
      const float ev[4] = {e4.x, e4.y, e4.z, e4.w};
#pragma unroll
      for (int u = 0; u < 4; ++u)
        T0[ii][cq + u] =
            adj_val(wv[u], inv, nv[u], ev[u], b, d, (i0 + ii) == (j0 + cq + u));
    }
    if (bi != bj) {
      const size_t off = (size_t)(j0 + ii) * kN + i0 + cq;
      const float4 w4 = *(const float4*)(&WSR[off]);
      const float4 n4 = *(const float4*)(&ne[off]);
      const float4 e4 = *(const float4*)(&epsm[off]);
      const float inv = invn[j0 + ii];
      const float wv[4] = {w4.x, w4.y, w4.z, w4.w};
      const float nv[4] = {n4.x, n4.y, n4.z, n4.w};
      const float ev[4] = {e4.x, e4.y, e4.z, e4.w};
#pragma unroll
      for (int u = 0; u < 4; ++u)
        T1[ii][cq + u] = adj_val(wv[u], inv, nv[u], ev[u], b, d, false);
    }
  }
  __syncthreads();
#pragma unroll
  for (int p = 0; p < 4; ++p) {
    const int jj = p * 16 + rlq;
    {
      const float4 v4 = make_float4(T0[cq + 0][jj], T0[cq + 1][jj],
                                    T0[cq + 2][jj], T0[cq + 3][jj]);
      ushort4v h4, m4;
      split2x4(v4, h4, m4);
      const size_t base = (size_t)(j0 + jj) * kN + i0 + cq;
      *(ushort4v*)(&Adj2[base]) = h4;
      *(ushort4v*)(&Adj2[PLANE_NN + base]) = m4;
    }
    if (bi != bj) {
      const float4 v4 = make_float4(T1[cq + 0][jj], T1[cq + 1][jj],
                                    T1[cq + 2][jj], T1[cq + 3][jj]);
      ushort4v h4, m4;
      split2x4(v4, h4, m4);
      const size_t base = (size_t)(i0 + jj) * kN + j0 + cq;
      *(ushort4v*)(&Adj2[base]) = h4;
      *(ushort4v*)(&Adj2[PLANE_NN + base]) = m4;
    }
  }
  if (tid < 64) {
    float s = 0.0f;
#pragma unroll 8
    for (int ii = 0; ii < 64; ++ii) s += T0[ii][tid];
    degp[(size_t)bi * kN + j0 + tid] = s;
    if (bi != bj) {
      float s1 = 0.0f;
#pragma unroll 8
      for (int ii = 0; ii < 64; ++ii) s1 += T1[ii][tid];
      degp[(size_t)bj * kN + i0 + tid] = s1;
    }
  }
}

__global__ __launch_bounds__(256) void deg_dis_kernel(
    const float* __restrict__ degp, float* __restrict__ dis) {
  const int j = blockIdx.x * 256 + threadIdx.x;
  float s = 0.0f;
#pragma unroll
  for (int c = 0; c < 64; ++c) s += degp[(size_t)c * kN + j];
  dis[j] = (s > 0.0f) ? (1.0f / sqrtf(s)) : 0.0f;
}

// ============ split-K combines ============
__global__ __launch_bounds__(256) void combine_h(
    const float* __restrict__ hp, const float* __restrict__ dis,
    const float* __restrict__ b0, const float* __restrict__ b1,
    unsigned short* __restrict__ h2) {
  const size_t qd = (size_t)blockIdx.x * 256 + threadIdx.x;
  const int m = (int)(qd >> 8);
  const int c0 = (int)(qd & 255) * 4;
  const size_t off = (size_t)m * 1024 + c0;
  const float4 s0 = *(const float4*)(&hp[off]);
  const float4 s1 = *(const float4*)(&hp[PLANE_H + off]);
  const float4 s2 = *(const float4*)(&hp[2 * PLANE_H + off]);
  const float4 s3 = *(const float4*)(&hp[3 * PLANE_H + off]);
  const float4 bv = (c0 < 512) ? *(const float4*)(&b0[c0])
                               : *(const float4*)(&b1[c0 - 512]);
  const float ds = dis[m];
  float4 v4;
  v4.x = fmaxf(ds * (s0.x + s1.x + s2.x + s3.x) + bv.x, 0.f);
  v4.y = fmaxf(ds * (s0.y + s1.y + s2.y + s3.y) + bv.y, 0.f);
  v4.z = fmaxf(ds * (s0.z + s1.z + s2.z + s3.z) + bv.z, 0.f);
  v4.w = fmaxf(ds * (s0.w + s1.w + s2.w + s3.w) + bv.w, 0.f);
  ushort4v h4, m4;
  split2x4(v4, h4, m4);
  *(ushort4v*)(&h2[off]) = h4;
  *(ushort4v*)(&h2[PLANE_H + off]) = m4;
}

__global__ __launch_bounds__(256) void combine_z(
    const float* __restrict__ zp, const float* __restrict__ dis,
    const float* __restrict__ b0, const float* __restrict__ b1,
    float* __restrict__ out) {
  const size_t qd = (size_t)blockIdx.x * 256 + threadIdx.x;
  const int m = (int)(qd >> 7);
  const int c0 = (int)(qd & 127) * 4;
  const size_t off = (size_t)m * 512 + c0;
  constexpr size_t PZ = (size_t)kN * 512;
  float4 acc = make_float4(0.f, 0.f, 0.f, 0.f);
#pragma unroll
  for (int s = 0; s < 8; ++s) {
    const float4 v = *(const float4*)(&zp[(size_t)s * PZ + off]);
    acc.x += v.x; acc.y += v.y; acc.z += v.z; acc.w += v.w;
  }
  const float4 bv = (c0 < 256) ? *(const float4*)(&b0[c0])
                               : *(const float4*)(&b1[c0 - 256]);
  const float ds = dis[m];
  float4 v4;
  v4.x = fmaxf(ds * acc.x + bv.x, 0.f);
  v4.y = fmaxf(ds * acc.y + bv.y, 0.f);
  v4.z = fmaxf(ds * acc.z + bv.z, 0.f);
  v4.w = fmaxf(ds * acc.w + bv.w, 0.f);
  float* dst = (c0 < 256) ? &out[(size_t)m * 256 + c0]
                          : &out[(size_t)kN * 256 + (size_t)m * 256 + (c0 - 256)];
  *(float4*)dst = v4;
}

// ============ launch ============
extern "C" void kernel_launch(void* const* d_in, const int* in_sizes, int n_in,
                              void* d_out, int out_size, void* d_ws,
                              size_t ws_size, hipStream_t stream) {
  const float* x = (const float*)d_in[0];
  const float* ne = (const float*)d_in[1];
  const float* beta = (const float*)d_in[2];
  const float* delta = (const float*)d_in[3];
  const float* epsm = (const float*)d_in[4];
  const float* Wm = (const float*)d_in[5];
  const float* bm = (const float*)d_in[6];
  const float* Ws = (const float*)d_in[7];
  const float* bs = (const float*)d_in[8];
  const float* mW0 = (const float*)d_in[9];
  const float* mb0 = (const float*)d_in[10];
  const float* mW1 = (const float*)d_in[11];
  const float* mb1 = (const float*)d_in[12];
  const float* sW0 = (const float*)d_in[13];
  const float* sb0 = (const float*)d_in[14];
  const float* sW1 = (const float*)d_in[15];
  const float* sb1 = (const float*)d_in[16];
  float* out = (float*)d_out;

  // WSR (67.1 MB) dead after adj_transpose; hp (67.1) and zp (67.1) alias it.
  char* p = (char*)d_ws;
  float* WSR = (float*)p;                     p += PLANE_NN * 4;
  unsigned short* Adj2 = (unsigned short*)p;  p += 2 * PLANE_NN * 2;
  unsigned short* x3 = (unsigned short*)p;    p += 3 * PLANE_XF * 2;  // -> V1t2
  float* XMf = (float*)p;                     p += PLANE_XF * 4;
  float* XSf = (float*)p;                     p += PLANE_XF * 4;
  unsigned short* XM2 = (unsigned short*)p;   p += 2 * PLANE_XF * 2;  // -> h2
  unsigned short* XS2 = (unsigned short*)p;   p += 2 * PLANE_XF * 2;
  unsigned short* M2 = (unsigned short*)p;    p += 2 * PLANE_XF * 2;  // -> V0t2
  unsigned short* CS2 = (unsigned short*)p;   p += 2 * PLANE_XF * 2;
  unsigned short* Wm3 = (unsigned short*)p;   p += 3 * PLANE_W * 2;
  unsigned short* Ws3 = (unsigned short*)p;   p += 3 * PLANE_W * 2;
  unsigned short* mW0t2 = (unsigned short*)p; p += 2 * PLANE_W * 2;
  unsigned short* sW0t2 = (unsigned short*)p; p += 2 * PLANE_W * 2;
  unsigned short* mW1t2 = (unsigned short*)p; p += 2 * PLANE_W1 * 2;
  unsigned short* sW1t2 = (unsigned short*)p; p += 2 * PLANE_W1 * 2;
  float* degp = (float*)p;                    p += (size_t)64 * kN * 4;
  float* rsqp = (float*)p;                    p += (size_t)32 * kN * 4;
  float* sq = (float*)p;                      p += kN * 4;
  float* csum = (float*)p;                    p += kN * 4;
  float* invn = (float*)p;                    p += kN * 4;
  float* dis = (float*)p;                     p += kN * 4;

  float* hp = WSR;   // 4 * PLANE_H floats = PLANE_NN floats exactly
  float* zp = WSR;   // 8 * kN*512 floats = PLANE_NN floats exactly
  unsigned short* V1t2 = x3;
  unsigned short* h2 = XM2;
  unsigned short* V0t2 = M2;

  const dim3 blk(256);
  const int nTri64 = (kN / 64) * (kN / 64 + 1) / 2;    // 2080 (adj)
  const int nTri128 = (kN / 128) * (kN / 128 + 1) / 2; // 528 (ws)

  prep_w<<<dim3(1024, 6), blk, 0, stream>>>(Wm, Ws, mW0, sW0, mW1, sW1, Wm3,
                                            Ws3, mW0t2, sW0t2, mW1t2, sW1t2);
  split_x<<<(kN * kF) / 256, blk, 0, stream>>>(x, x3);

  // 1) x_mean/x_std (split3, full precision) -> f32
  gemm_x<<<dim3(16, 32), blk, 0, stream>>>(x3, Wm3, Ws3, XMf, XSf, bm, bs);

  // 2) row stats + all split2 planes
  row_stats<<<kN, blk, 0, stream>>>(XMf, XSf, M2, CS2, XM2, XS2, sq, csum);

  // 3) ws_raw (128-tiles, triangle + mirror) + row-sumsq partials
  ws_mfma2<<<nTri128, blk, 0, stream>>>(M2, CS2, sq, csum, WSR, rsqp);

  // 4) invn from partials (no full-matrix re-read)
  invn_from_rsqp<<<kN / 256, blk, 0, stream>>>(rsqp, invn);

  // 5) adjacency -> Adj2 (transposed 2-plane) + deg partials. WSR dead after.
  adj_transpose<<<nTri64, blk, 0, stream>>>(WSR, invn, ne, epsm, beta, delta,
                                            Adj2, degp);
  deg_dis_kernel<<<kN / 256, blk, 0, stream>>>(degp, dis);

  // 6) V0t = (dis_i * XM@W0 | XS@W0)^T  -> split2 CT planes [1024][4096]
  gemm2ct<128, 64><<<dim3(16, 32), blk, 0, stream>>>(
      XM2, XS2, kF, PLANE_XF, mW0t2, sW0t2, kF, PLANE_W, V0t2,
      V0t2 + (size_t)512 * kN, kN, PLANE_V0, 512, kF, dis);

  // 7) h partials: AdjT @ V0t, split-K=4, XCD-swizzled (8*8*4*4 = 1024 blocks)
  gemm2k<128, 128, 8, 4, 4><<<1024, blk, 0, stream>>>(
      Adj2, kN, PLANE_NN, V0t2, kN, PLANE_V0, hp, 1024, kN, kN / 4);
  combine_h<<<(int)(PLANE_H / 4 / 256), blk, 0, stream>>>(hp, dis, mb0, sb0, h2);

  // 8) V1t = (dis_i * h@W1)^T -> split2 CT planes [512][4096]
  gemm2ct<64, 64><<<dim3(8, 64), blk, 0, stream>>>(
      h2, h2 + 512, 1024, PLANE_H, mW1t2, sW1t2, kF, PLANE_W1, V1t2,
      V1t2 + (size_t)256 * kN, kN, PLANE_V1, 256, kF, dis);

  // 9) z partials: AdjT @ V1t, split-K=8, XCD-swizzled (8*4*4*8 = 1024 blocks)
  gemm2k<128, 128, 4, 4, 8><<<1024, blk, 0, stream>>>(
      Adj2, kN, PLANE_NN, V1t2, kN, PLANE_V1, zp, 512, kN, kN / 8);
  combine_z<<<(int)((size_t)kN * 512 / 4 / 256), blk, 0, stream>>>(zp, dis, mb1,
                                                                   sb1, out);
}

// Round 10
// 700.123 us; speedup vs baseline: 1.0172x; 1.0172x over previous
//
#include <hip/hip_runtime.h>
#include <cstddef>

static constexpr int kN = 4096;
static constexpr int kF = 512;
static constexpr int kH = 256;
static constexpr float kClamp = 1e-6f;

using bf16x8 = __attribute__((ext_vector_type(8))) __bf16;
using f32x4 = __attribute__((ext_vector_type(4))) float;
using ushort8 = __attribute__((ext_vector_type(8))) unsigned short;
using ushort4v = __attribute__((ext_vector_type(4))) unsigned short;

static constexpr size_t PLANE_XF = (size_t)kN * kF;      // 2.1M
static constexpr size_t PLANE_NN = (size_t)kN * kN;      // 16.8M
static constexpr size_t PLANE_W = (size_t)512 * 512;
static constexpr size_t PLANE_W1 = (size_t)256 * 512;
static constexpr size_t PLANE_V0 = (size_t)1024 * kN;
static constexpr size_t PLANE_H = (size_t)kN * 1024;
static constexpr size_t PLANE_V1 = (size_t)512 * kN;

__device__ __forceinline__ unsigned short f2bf(float x) {
  unsigned int u = __float_as_uint(x);
  u += 0x7fffu + ((u >> 16) & 1u);
  return (unsigned short)(u >> 16);
}
__device__ __forceinline__ float bf2f(unsigned short h) {
  return __uint_as_float(((unsigned int)h) << 16);
}
__device__ __forceinline__ void split3(float x, unsigned short& h,
                                       unsigned short& m, unsigned short& l) {
  h = f2bf(x);
  const float r1 = x - bf2f(h);
  m = f2bf(r1);
  l = f2bf(r1 - bf2f(m));
}
__device__ __forceinline__ void split2(float x, unsigned short& h,
                                       unsigned short& m) {
  h = f2bf(x);
  m = f2bf(x - bf2f(h));
}
__device__ __forceinline__ void split2x4(const float4 v, ushort4v& h4,
                                         ushort4v& m4) {
  unsigned short h, m;
  split2(v.x, h, m); h4.x = h; m4.x = m;
  split2(v.y, h, m); h4.y = h; m4.y = m;
  split2(v.z, h, m); h4.z = h; m4.z = m;
  split2(v.w, h, m); h4.w = h; m4.w = m;
}

__device__ __forceinline__ bf16x8 ldfrag(const unsigned short* p) {
  ushort8 r = *(const ushort8*)p;
  return __builtin_bit_cast(bf16x8, r);
}
__device__ __forceinline__ f32x4 mfma16(bf16x8 a, bf16x8 b, f32x4 c) {
  return __builtin_amdgcn_mfma_f32_16x16x32_bf16(a, b, c, 0, 0, 0);
}
// 6-product (split3): rel err ~2^-26
__device__ __forceinline__ f32x4 mfma_split6(const bf16x8* a3, const bf16x8* b3,
                                             f32x4 acc) {
  acc = mfma16(a3[2], b3[0], acc);
  acc = mfma16(a3[0], b3[2], acc);
  acc = mfma16(a3[1], b3[1], acc);
  acc = mfma16(a3[1], b3[0], acc);
  acc = mfma16(a3[0], b3[1], acc);
  acc = mfma16(a3[0], b3[0], acc);
  return acc;
}

__device__ __forceinline__ void tri_map(int b, int& bi, int& bj) {
  int x = (int)((sqrtf(8.0f * (float)b + 1.0f) - 1.0f) * 0.5f);
  while ((x + 1) * (x + 2) / 2 <= b) ++x;
  while (x * (x + 1) / 2 > b) --x;
  bi = x;
  bj = b - x * (x + 1) / 2;
}

__device__ __forceinline__ float block_reduce_sum(float v, float* sbuf) {
  const int tid = threadIdx.x;
  sbuf[tid] = v;
  __syncthreads();
#pragma unroll
  for (int s = 128; s > 0; s >>= 1) {
    if (tid < s) sbuf[tid] += sbuf[tid + s];
    __syncthreads();
  }
  const float r = sbuf[0];
  __syncthreads();
  return r;
}

// ============ prep: transpose+split weights ============
__global__ __launch_bounds__(256) void prep_w(
    const float* s0, const float* s1, const float* s2, const float* s3,
    const float* s4, const float* s5, unsigned short* d0, unsigned short* d1,
    unsigned short* d2, unsigned short* d3, unsigned short* d4,
    unsigned short* d5) {
  const int seg = blockIdx.y;
  const float* src;
  unsigned short* dst;
  int N;
  bool tri;
  switch (seg) {
    case 0: src = s0; dst = d0; N = 512; tri = true; break;
    case 1: src = s1; dst = d1; N = 512; tri = true; break;
    case 2: src = s2; dst = d2; N = 512; tri = false; break;
    case 3: src = s3; dst = d3; N = 512; tri = false; break;
    case 4: src = s4; dst = d4; N = 256; tri = false; break;
    default: src = s5; dst = d5; N = 256; tri = false; break;
  }
  const int id = blockIdx.x * 256 + threadIdx.x;
  if (id >= 512 * N) return;
  const int k = id & 511;
  const int n = id >> 9;
  const float v = src[(size_t)k * N + n];
  const size_t base = (size_t)n * 512 + k;
  const size_t plane = (size_t)512 * N;
  if (tri) {
    unsigned short h, m, l;
    split3(v, h, m, l);
    dst[base] = h;
    dst[plane + base] = m;
    dst[2 * plane + base] = l;
  } else {
    unsigned short h, m;
    split2(v, h, m);
    dst[base] = h;
    dst[plane + base] = m;
  }
}

// ============ split x into 3 planes ============
__global__ __launch_bounds__(256) void split_x(const float* __restrict__ x,
                                               unsigned short* __restrict__ x3) {
  const size_t id = (size_t)blockIdx.x * 256 + threadIdx.x;
  unsigned short h, m, l;
  split3(x[id], h, m, l);
  x3[id] = h;
  x3[PLANE_XF + id] = m;
  x3[2 * PLANE_XF + id] = l;
}

// ============ GEMM-1 (split3, 6-product): x@Wm|Ws -> XMf|XSf (f32) ============
__global__ __launch_bounds__(256) void gemm_x(
    const unsigned short* __restrict__ A3, const unsigned short* __restrict__ B30,
    const unsigned short* __restrict__ B31, float* __restrict__ C0,
    float* __restrict__ C1, const float* __restrict__ bias0,
    const float* __restrict__ bias1) {
  constexpr int BM = 128, BN = 64, K = 512;
  __shared__ __align__(16) unsigned short Asl[3][BM][40];
  __shared__ __align__(16) unsigned short Bsl[3][BN][40];
  const int tid = threadIdx.x;
  const int lane = tid & 63;
  const int wave = tid >> 6;
  const int wm = wave >> 1, wn = wave & 1;
  const int m0 = blockIdx.y * BM;
  const int n0 = blockIdx.x * BN;
  const bool str1 = (n0 >= 512);
  const int nloc = str1 ? (n0 - 512) : n0;
  const unsigned short* Bb = str1 ? B31 : B30;
  const float* bias = str1 ? bias1 : bias0;
  float* C = str1 ? C1 : C0;
  const int rl = lane & 15;
  const int kq = (lane >> 4) * 8;
  const int q = lane >> 4;

  f32x4 acc[4][2];
#pragma unroll
  for (int i = 0; i < 4; ++i)
#pragma unroll
    for (int j = 0; j < 2; ++j) acc[i][j] = (f32x4){0.f, 0.f, 0.f, 0.f};

  for (int k0 = 0; k0 < K; k0 += 32) {
#pragma unroll
    for (int it = 0; it < 6; ++it) {
      const int c = tid + it * 256;
      const int plane = c / (BM * 4);
      const int rem = c % (BM * 4);
      const int row = rem >> 2;
      const int kc = (rem & 3) * 8;
      const ushort8 v = *(const ushort8*)(&A3[(size_t)plane * PLANE_XF +
                                              (size_t)(m0 + row) * K + k0 + kc]);
      *(ushort8*)(&Asl[plane][row][kc]) = v;
    }
#pragma unroll
    for (int it = 0; it < 3; ++it) {
      const int c = tid + it * 256;
      const int plane = c / (BN * 4);
      const int rem = c % (BN * 4);
      const int row = rem >> 2;
      const int kc = (rem & 3) * 8;
      const ushort8 v = *(const ushort8*)(&Bb[(size_t)plane * PLANE_W +
                                              (size_t)(nloc + row) * K + k0 + kc]);
      *(ushort8*)(&Bsl[plane][row][kc]) = v;
    }
    __syncthreads();
    bf16x8 af[4][3], bfr[2][3];
#pragma unroll
    for (int mt = 0; mt < 4; ++mt)
#pragma unroll
      for (int t = 0; t < 3; ++t)
        af[mt][t] = ldfrag(&Asl[t][wm * 64 + mt * 16 + rl][kq]);
#pragma unroll
    for (int nt = 0; nt < 2; ++nt)
#pragma unroll
      for (int t = 0; t < 3; ++t)
        bfr[nt][t] = ldfrag(&Bsl[t][wn * 32 + nt * 16 + rl][kq]);
#pragma unroll
    for (int mt = 0; mt < 4; ++mt)
#pragma unroll
      for (int nt = 0; nt < 2; ++nt)
        acc[mt][nt] = mfma_split6(af[mt], bfr[nt], acc[mt][nt]);
    __syncthreads();
  }
#pragma unroll
  for (int mt = 0; mt < 4; ++mt)
#pragma unroll
    for (int nt = 0; nt < 2; ++nt) {
      const int col = nloc + wn * 32 + nt * 16 + rl;
      const int row0 = m0 + wm * 64 + mt * 16 + q * 4;
      const float bv = bias[col];
#pragma unroll
      for (int r = 0; r < 4; ++r)
        C[(size_t)(row0 + r) * 512 + col] = acc[mt][nt][r] + bv;
    }
}

// ============ split2 3-product GEMM, CT-split2 output (small GEMMs) ============
template <int BM, int BN>
__global__ __launch_bounds__(256) void gemm2ct(
    const unsigned short* __restrict__ A0, const unsigned short* __restrict__ A1,
    int lda, size_t planeA, const unsigned short* __restrict__ B0,
    const unsigned short* __restrict__ B1, int ldb, size_t planeB,
    unsigned short* __restrict__ Cs0, unsigned short* __restrict__ Cs1, int ldc,
    size_t planeC, int N1, int K, const float* __restrict__ rowScale) {
  __shared__ __align__(16) unsigned short Asl[2][BM][40];
  __shared__ __align__(16) unsigned short Bsl[2][BN][40];
  const int tid = threadIdx.x;
  const int lane = tid & 63;
  const int wave = tid >> 6;
  const int wm = wave >> 1, wn = wave & 1;
  const int m0 = blockIdx.y * BM;
  const int n0 = blockIdx.x * BN;
  const bool str1 = (n0 >= N1);
  const int nloc = str1 ? (n0 - N1) : n0;
  const unsigned short* Ab = str1 ? A1 : A0;
  const unsigned short* Bb = str1 ? B1 : B0;
  const int rl = lane & 15;
  const int kq = (lane >> 4) * 8;
  const int q = lane >> 4;
  constexpr int MT = BM / 32;
  constexpr int NT = BN / 32;

  f32x4 acc[MT][NT];
#pragma unroll
  for (int i = 0; i < MT; ++i)
#pragma unroll
    for (int j = 0; j < NT; ++j) acc[i][j] = (f32x4){0.f, 0.f, 0.f, 0.f};

  for (int k0 = 0; k0 < K; k0 += 32) {
    constexpr int AIT = (2 * BM * 4) / 256;
#pragma unroll
    for (int it = 0; it < AIT; ++it) {
      const int c = tid + it * 256;
      const int plane = c / (BM * 4);
      const int rem = c % (BM * 4);
      const int row = rem >> 2;
      const int kc = (rem & 3) * 8;
      const ushort8 v = *(const ushort8*)(&Ab[(size_t)plane * planeA +
                                              (size_t)(m0 + row) * lda + k0 + kc]);
      *(ushort8*)(&Asl[plane][row][kc]) = v;
    }
    constexpr int BIT = (2 * BN * 4) / 256;
#pragma unroll
    for (int it = 0; it < BIT; ++it) {
      const int c = tid + it * 256;
      const int plane = c / (BN * 4);
      const int rem = c % (BN * 4);
      const int row = rem >> 2;
      const int kc = (rem & 3) * 8;
      const ushort8 v = *(const ushort8*)(&Bb[(size_t)plane * planeB +
                                              (size_t)(nloc + row) * ldb + k0 + kc]);
      *(ushort8*)(&Bsl[plane][row][kc]) = v;
    }
    __syncthreads();
    bf16x8 af[MT][2];
#pragma unroll
    for (int mt = 0; mt < MT; ++mt)
#pragma unroll
      for (int t = 0; t < 2; ++t)
        af[mt][t] = ldfrag(&Asl[t][wm * (BM / 2) + mt * 16 + rl][kq]);
#pragma unroll
    for (int nt = 0; nt < NT; ++nt) {
      const bf16x8 b0 = ldfrag(&Bsl[0][wn * (BN / 2) + nt * 16 + rl][kq]);
      const bf16x8 b1 = ldfrag(&Bsl[1][wn * (BN / 2) + nt * 16 + rl][kq]);
#pragma unroll
      for (int mt = 0; mt < MT; ++mt) {
        acc[mt][nt] = mfma16(af[mt][1], b0, acc[mt][nt]);
        acc[mt][nt] = mfma16(af[mt][0], b1, acc[mt][nt]);
        acc[mt][nt] = mfma16(af[mt][0], b0, acc[mt][nt]);
      }
    }
    __syncthreads();
  }

#pragma unroll
  for (int mt = 0; mt < MT; ++mt) {
#pragma unroll
    for (int nt = 0; nt < NT; ++nt) {
      const int colL = nloc + wn * (BN / 2) + nt * 16 + rl;
      const int row0 = m0 + wm * (BM / 2) + mt * 16 + q * 4;
      float4 v4;
      float* vp = &v4.x;
#pragma unroll
      for (int r = 0; r < 4; ++r) {
        float v = acc[mt][nt][r];
        if (rowScale) v *= rowScale[row0 + r];
        vp[r] = v;
      }
      unsigned short* C = str1 ? Cs1 : Cs0;
      ushort4v h4, m4;
      split2x4(v4, h4, m4);
      const size_t base = (size_t)colL * ldc + row0;
      *(ushort4v*)(&C[base]) = h4;
      *(ushort4v*)(&C[planeC + base]) = m4;
    }
  }
}

// ============ split2 3-product GEMM, split-K partials, XCD-swizzled ============
template <int BM, int BN, int GX, int GYP, int GZ>
__global__ __launch_bounds__(256) void gemm2k(
    const unsigned short* __restrict__ A, int lda, size_t planeA,
    const unsigned short* __restrict__ B, int ldb, size_t planeB,
    float* __restrict__ Cp, int ldc, int Mtot, int Ksl) {
  __shared__ __align__(16) unsigned short Asl[2][BM][40];
  __shared__ __align__(16) unsigned short Bsl[2][BN][40];
  const int lin = blockIdx.x;
  const int xcd = lin & 7;
  const int s = lin >> 3;
  constexpr int per = GX * GYP;
  const int z = s / per;
  const int r = s - z * per;
  const int bx = r % GX;
  const int by = xcd * GYP + r / GX;
  const int m0 = by * BM;
  const int n0 = bx * BN;
  const int kOff = z * Ksl;

  const int tid = threadIdx.x;
  const int lane = tid & 63;
  const int wave = tid >> 6;
  const int wm = wave >> 1, wn = wave & 1;
  const int rl = lane & 15;
  const int kq = (lane >> 4) * 8;
  const int q = lane >> 4;
  constexpr int MT = BM / 32;
  constexpr int NT = BN / 32;

  f32x4 acc[MT][NT];
#pragma unroll
  for (int i = 0; i < MT; ++i)
#pragma unroll
    for (int j = 0; j < NT; ++j) acc[i][j] = (f32x4){0.f, 0.f, 0.f, 0.f};

  for (int k0 = 0; k0 < Ksl; k0 += 32) {
    constexpr int AIT = (2 * BM * 4) / 256;
#pragma unroll
    for (int it = 0; it < AIT; ++it) {
      const int c = tid + it * 256;
      const int plane = c / (BM * 4);
      const int rem = c % (BM * 4);
      const int row = rem >> 2;
      const int kc = (rem & 3) * 8;
      const ushort8 v = *(const ushort8*)(&A[(size_t)plane * planeA +
                                             (size_t)(m0 + row) * lda + kOff +
                                             k0 + kc]);
      *(ushort8*)(&Asl[plane][row][kc]) = v;
    }
    constexpr int BIT = (2 * BN * 4) / 256;
#pragma unroll
    for (int it = 0; it < BIT; ++it) {
      const int c = tid + it * 256;
      const int plane = c / (BN * 4);
      const int rem = c % (BN * 4);
      const int row = rem >> 2;
      const int kc = (rem & 3) * 8;
      const ushort8 v = *(const ushort8*)(&B[(size_t)plane * planeB +
                                             (size_t)(n0 + row) * ldb + kOff +
                                             k0 + kc]);
      *(ushort8*)(&Bsl[plane][row][kc]) = v;
    }
    __syncthreads();
    bf16x8 af[MT][2];
#pragma unroll
    for (int mt = 0; mt < MT; ++mt)
#pragma unroll
      for (int t = 0; t < 2; ++t)
        af[mt][t] = ldfrag(&Asl[t][wm * (BM / 2) + mt * 16 + rl][kq]);
#pragma unroll
    for (int nt = 0; nt < NT; ++nt) {
      const bf16x8 b0 = ldfrag(&Bsl[0][wn * (BN / 2) + nt * 16 + rl][kq]);
      const bf16x8 b1 = ldfrag(&Bsl[1][wn * (BN / 2) + nt * 16 + rl][kq]);
#pragma unroll
      for (int mt = 0; mt < MT; ++mt) {
        acc[mt][nt] = mfma16(af[mt][1], b0, acc[mt][nt]);
        acc[mt][nt] = mfma16(af[mt][0], b1, acc[mt][nt]);
        acc[mt][nt] = mfma16(af[mt][0], b0, acc[mt][nt]);
      }
    }
    __syncthreads();
  }

  const size_t zoff = (size_t)z * (size_t)Mtot * (size_t)ldc;
#pragma unroll
  for (int mt = 0; mt < MT; ++mt) {
#pragma unroll
    for (int nt = 0; nt < NT; ++nt) {
      const int colL = n0 + wn * (BN / 2) + nt * 16 + rl;
      const int row0 = m0 + wm * (BM / 2) + mt * 16 + q * 4;
#pragma unroll
      for (int r = 0; r < 4; ++r)
        Cp[zoff + (size_t)(row0 + r) * ldc + colL] = acc[mt][nt][r];
    }
  }
}

// ============ row stats: XMf/XSf f32 -> M2/CS2/XM2/XS2 planes ============
__global__ __launch_bounds__(256) void row_stats(
    const float* __restrict__ XMf, const float* __restrict__ XSf,
    unsigned short* __restrict__ M2, unsigned short* __restrict__ CS2,
    unsigned short* __restrict__ XM2, unsigned short* __restrict__ XS2,
    float* __restrict__ sq, float* __restrict__ csum) {
  __shared__ float sbuf[256];
  const int i = blockIdx.x;
  const int tid = threadIdx.x;
  const size_t base = (size_t)i * kF;
  const size_t i0 = base + tid, i1 = base + tid + 256;
  const float x0 = XMf[i0], x1 = XMf[i1];
  {
    unsigned short h, m;
    split2(x0, h, m);
    XM2[i0] = h; XM2[PLANE_XF + i0] = m;
    split2(x1, h, m);
    XM2[i1] = h; XM2[PLANE_XF + i1] = m;
  }
  const float nrm = block_reduce_sum(x0 * x0 + x1 * x1, sbuf);
  const float inv = 1.0f / fmaxf(sqrtf(nrm), 1e-12f);
  const float m0 = x0 * inv, m1 = x1 * inv;
  {
    unsigned short h, m;
    split2(m0, h, m);
    M2[i0] = h; M2[PLANE_XF + i0] = m;
    split2(m1, h, m);
    M2[i1] = h; M2[PLANE_XF + i1] = m;
  }
  const float s2 = block_reduce_sum(m0 * m0 + m1 * m1, sbuf);
  if (tid == 0) sq[i] = s2;

  const float y0 = XSf[i0], y1 = XSf[i1];
  {
    unsigned short h, m;
    split2(y0, h, m);
    XS2[i0] = h; XS2[PLANE_XF + i0] = m;
    split2(y1, h, m);
    XS2[i1] = h; XS2[PLANE_XF + i1] = m;
  }
  const float e0 = expf(y0), e1 = expf(y1);
  const float nrm2 = block_reduce_sum(e0 * e0 + e1 * e1, sbuf);
  const float inv2 = 1.0f / fmaxf(sqrtf(nrm2), 1e-12f);
  const float c0 = e0 * inv2, c1 = e1 * inv2;
  const float sc = block_reduce_sum(c0 + c1, sbuf);
  if (tid == 0) csum[i] = sc;
  {
    unsigned short h, m;
    split2(sqrtf(c0), h, m);
    CS2[i0] = h; CS2[PLANE_XF + i0] = m;
    split2(sqrtf(c1), h, m);
    CS2[i1] = h; CS2[PLANE_XF + i1] = m;
  }
}

// ============ symmetric dual NT-GEMM, 128x128 tiles, 3-prod split2 ============
// Plane-interleaved LDS rows (stride 72 ushorts = 144 B): plane p of op o at
// S[o][row][p*32 + k]. 72 KiB total -> 2 blocks/CU. Start bank = (36r+16p+kq/2)
// mod 32 -> 2-way max (free, m136). Emits row/col sumsq partials (rsqp).
__global__ __launch_bounds__(256, 2) void ws_mfma2(
    const unsigned short* __restrict__ M2, const unsigned short* __restrict__ CS2,
    const float* __restrict__ sq, const float* __restrict__ csum,
    float* __restrict__ WSR, float* __restrict__ rsqp) {
  __shared__ __align__(16) unsigned short S[4][128][72];  // 72 KiB
  int bi, bj;
  tri_map(blockIdx.x, bi, bj);  // 32x32 tile grid, bi >= bj
  const int i0 = bi * 128, j0 = bj * 128;
  const int tid = threadIdx.x;
  const int lane = tid & 63;
  const int wave = tid >> 6;
  const int wm = wave >> 1, wn = wave & 1;
  const int rl = lane & 15;
  const int kq = (lane >> 4) * 8;
  const int q = lane >> 4;

  f32x4 aM[4][4], aC[4][4];
#pragma unroll
  for (int i = 0; i < 4; ++i)
#pragma unroll
    for (int j = 0; j < 4; ++j) {
      aM[i][j] = (f32x4){0.f, 0.f, 0.f, 0.f};
      aC[i][j] = (f32x4){0.f, 0.f, 0.f, 0.f};
    }

  for (int k0 = 0; k0 < kF; k0 += 32) {
    // stage 4 ops x 2 planes x 128 rows x 32 k  (4096 ushort8 slots)
#pragma unroll
    for (int it = 0; it < 16; ++it) {
      const int c = tid + it * 256;
      const int op = c >> 10;
      const int rem = c & 1023;
      const int plane = rem >> 9;
      const int r2 = rem & 511;
      const int row = r2 >> 2;
      const int kc = (r2 & 3) * 8;
      const unsigned short* mat = (op & 1) ? CS2 : M2;
      const int rowoff = (op < 2) ? i0 : j0;
      const ushort8 v = *(const ushort8*)(&mat[(size_t)plane * PLANE_XF +
                                               (size_t)(rowoff + row) * kF + k0 +
                                               kc]);
      *(ushort8*)(&S[op][row][plane * 32 + kc]) = v;
    }
    __syncthreads();
    {
      bf16x8 a_[4][2], b_[4][2];
#pragma unroll
      for (int mt = 0; mt < 4; ++mt)
#pragma unroll
        for (int t = 0; t < 2; ++t)
          a_[mt][t] = ldfrag(&S[0][wm * 64 + mt * 16 + rl][t * 32 + kq]);
#pragma unroll
      for (int nt = 0; nt < 4; ++nt)
#pragma unroll
        for (int t = 0; t < 2; ++t)
          b_[nt][t] = ldfrag(&S[2][wn * 64 + nt * 16 + rl][t * 32 + kq]);
#pragma unroll
      for (int mt = 0; mt < 4; ++mt)
#pragma unroll
        for (int nt = 0; nt < 4; ++nt) {
          aM[mt][nt] = mfma16(a_[mt][1], b_[nt][0], aM[mt][nt]);
          aM[mt][nt] = mfma16(a_[mt][0], b_[nt][1], aM[mt][nt]);
          aM[mt][nt] = mfma16(a_[mt][0], b_[nt][0], aM[mt][nt]);
        }
    }
    {
      bf16x8 a_[4][2], b_[4][2];
#pragma unroll
      for (int mt = 0; mt < 4; ++mt)
#pragma unroll
        for (int t = 0; t < 2; ++t)
          a_[mt][t] = ldfrag(&S[1][wm * 64 + mt * 16 + rl][t * 32 + kq]);
#pragma unroll
      for (int nt = 0; nt < 4; ++nt)
#pragma unroll
        for (int t = 0; t < 2; ++t)
          b_[nt][t] = ldfrag(&S[3][wn * 64 + nt * 16 + rl][t * 32 + kq]);
#pragma unroll
      for (int mt = 0; mt < 4; ++mt)
#pragma unroll
        for (int nt = 0; nt < 4; ++nt) {
          aC[mt][nt] = mfma16(a_[mt][1], b_[nt][0], aC[mt][nt]);
          aC[mt][nt] = mfma16(a_[mt][0], b_[nt][1], aC[mt][nt]);
          aC[mt][nt] = mfma16(a_[mt][0], b_[nt][0], aC[mt][nt]);
        }
    }
    __syncthreads();
  }

  // epilogue: reuse S memory for row/col sum-of-squares reduction
  float* rs_ = (float*)&S[0][0][0];  // [128] row partials (direct tile)
  float* cs_ = rs_ + 128;            // [128] col partials (mirror rows)
  if (tid < 256) rs_[tid] = 0.f;
  __syncthreads();

  float rowacc[4][4];
  float colacc[4];
#pragma unroll
  for (int i = 0; i < 4; ++i) {
    colacc[i] = 0.f;
#pragma unroll
    for (int j = 0; j < 4; ++j) rowacc[i][j] = 0.f;
  }

#pragma unroll
  for (int mt = 0; mt < 4; ++mt) {
#pragma unroll
    for (int nt = 0; nt < 4; ++nt) {
      const int j = j0 + wn * 64 + nt * 16 + rl;
      const int ib = i0 + wm * 64 + mt * 16 + q * 4;
      const float sqj = sq[j], csj = csum[j];
      float4 vv;
      float* vp = &vv.x;
#pragma unroll
      for (int r = 0; r < 4; ++r) {
        const int i = ib + r;
        const float d2 = fmaxf(sq[i] + sqj - 2.0f * aM[mt][nt][r], 0.0f);
        const float res = d2 + csum[i] + csj - 2.0f * aC[mt][nt][r];
        const float v = expf(-res);
        vp[r] = v;
        WSR[(size_t)i * kN + j] = v;
        rowacc[mt][r] += v * v;
        colacc[nt] += v * v;
      }
      if (bi != bj) *(float4*)(&WSR[(size_t)j * kN + ib]) = vv;
    }
  }
#pragma unroll
  for (int mt = 0; mt < 4; ++mt)
#pragma unroll
    for (int r = 0; r < 4; ++r)
      atomicAdd(&rs_[wm * 64 + mt * 16 + q * 4 + r], rowacc[mt][r]);
#pragma unroll
  for (int nt = 0; nt < 4; ++nt)
    atomicAdd(&cs_[wn * 64 + nt * 16 + rl], colacc[nt]);
  __syncthreads();
  if (tid < 128) {
    rsqp[(size_t)bj * kN + i0 + tid] = rs_[tid];
    if (bi != bj) rsqp[(size_t)bi * kN + j0 + tid] = cs_[tid];
  }
}

// ============ invn from rsqp slabs ============
__global__ __launch_bounds__(256) void invn_from_rsqp(
    const float* __restrict__ rsqp, float* __restrict__ invn) {
  const int i = blockIdx.x * 256 + threadIdx.x;
  float s = 0.0f;
#pragma unroll
  for (int c = 0; c < 32; ++c) s += rsqp[(size_t)c * kN + i];
  invn[i] = 1.0f / fmaxf(sqrtf(s), 1e-12f);
}

// ============ adjacency transform + transposed 2-plane split + deg ============
__device__ __forceinline__ float adj_val(float w, float inv, float nev, float ev,
                                         float b, float d, bool diag) {
  float t = (1.0f - b) * (w * inv) + b * nev;
  t = fminf(fmaxf(t, kClamp), 1.0f - kClamp);
  float L = logf(t / (1.0f - t));
  const float e = fminf(fmaxf(ev, kClamp), 1.0f - kClamp);
  L += logf(e / (1.0f - e));
  const float s = 1.0f / (1.0f + expf(-L));
  float v = (s > d) ? s : 0.0f;
  if (diag) v = (v > 0.0f) ? v : 1.0f;
  return v;
}

__global__ __launch_bounds__(256) void adj_transpose(
    const float* __restrict__ WSR, const float* __restrict__ invn,
    const float* __restrict__ ne, const float* __restrict__ epsm,
    const float* __restrict__ beta_p, const float* __restrict__ delta_p,
    unsigned short* __restrict__ Adj2, float* __restrict__ degp) {
  __shared__ float T0[64][65];
  __shared__ float T1[64][65];
  const float b = beta_p[0];
  const float d = delta_p[0];
  int bi, bj;
  tri_map(blockIdx.x, bi, bj);
  const int i0 = bi * 64, j0 = bj * 64;
  const int tid = threadIdx.x;
  const int rlq = tid >> 4;
  const int cq = (tid & 15) * 4;
#pragma unroll
  for (int p = 0; p < 4; ++p) {
    const int ii = p * 16 + rlq;
    {
      const size_t off = (size_t)(i0 + ii) * kN + j0 + cq;
      const float4 w4 = *(const float4*)(&WSR[off]);
      const float4 n4 = *(const float4*)(&ne[off]);
      const float4 e4 = *(const float4*)(&epsm[off]);
      const float inv = invn[i0 + ii];
      const float wv[4] = {w4.x, w4.y, w4.z, w4.w};
      const float nv[4] = {n4.x, n4.y, n4.z, n4.w};
      const float ev[4] = {e4.x, e4.y, e4.z, e4.w};
#pragma unroll
      for (int u = 0; u < 4; ++u)
        T0[ii][cq + u] =
            adj_val(wv[u], inv, nv[u], ev[u], b, d, (i0 + ii) == (j0 + cq + u));
    }
    if (bi != bj) {
      const size_t off = (size_t)(j0 + ii) * kN + i0 + cq;
      const float4 w4 = *(const float4*)(&WSR[off]);
      const float4 n4 = *(const float4*)(&ne[off]);
      const float4 e4 = *(const float4*)(&epsm[off]);
      const float inv = invn[j0 + ii];
      const float wv[4] = {w4.x, w4.y, w4.z, w4.w};
      const float nv[4] = {n4.x, n4.y, n4.z, n4.w};
      const float ev[4] = {e4.x, e4.y, e4.z, e4.w};
#pragma unroll
      for (int u = 0; u < 4; ++u)
        T1[ii][cq + u] = adj_val(wv[u], inv, nv[u], ev[u], b, d, false);
    }
  }
  __syncthreads();
#pragma unroll
  for (int p = 0; p < 4; ++p) {
    const int jj = p * 16 + rlq;
    {
      const float4 v4 = make_float4(T0[cq + 0][jj], T0[cq + 1][jj],
                                    T0[cq + 2][jj], T0[cq + 3][jj]);
      ushort4v h4, m4;
      split2x4(v4, h4, m4);
      const size_t base = (size_t)(j0 + jj) * kN + i0 + cq;
      *(ushort4v*)(&Adj2[base]) = h4;
      *(ushort4v*)(&Adj2[PLANE_NN + base]) = m4;
    }
    if (bi != bj) {
      const float4 v4 = make_float4(T1[cq + 0][jj], T1[cq + 1][jj],
                                    T1[cq + 2][jj], T1[cq + 3][jj]);
      ushort4v h4, m4;
      split2x4(v4, h4, m4);
      const size_t base = (size_t)(i0 + jj) * kN + j0 + cq;
      *(ushort4v*)(&Adj2[base]) = h4;
      *(ushort4v*)(&Adj2[PLANE_NN + base]) = m4;
    }
  }
  if (tid < 64) {
    float s = 0.0f;
#pragma unroll 8
    for (int ii = 0; ii < 64; ++ii) s += T0[ii][tid];
    degp[(size_t)bi * kN + j0 + tid] = s;
    if (bi != bj) {
      float s1 = 0.0f;
#pragma unroll 8
      for (int ii = 0; ii < 64; ++ii) s1 += T1[ii][tid];
      degp[(size_t)bj * kN + i0 + tid] = s1;
    }
  }
}

__global__ __launch_bounds__(256) void deg_dis_kernel(
    const float* __restrict__ degp, float* __restrict__ dis) {
  const int j = blockIdx.x * 256 + threadIdx.x;
  float s = 0.0f;
#pragma unroll
  for (int c = 0; c < 64; ++c) s += degp[(size_t)c * kN + j];
  dis[j] = (s > 0.0f) ? (1.0f / sqrtf(s)) : 0.0f;
}

// ============ split-K combines ============
__global__ __launch_bounds__(256) void combine_h(
    const float* __restrict__ hp, const float* __restrict__ dis,
    const float* __restrict__ b0, const float* __restrict__ b1,
    unsigned short* __restrict__ h2) {
  const size_t qd = (size_t)blockIdx.x * 256 + threadIdx.x;
  const int m = (int)(qd >> 8);
  const int c0 = (int)(qd & 255) * 4;
  const size_t off = (size_t)m * 1024 + c0;
  const float4 s0 = *(const float4*)(&hp[off]);
  const float4 s1 = *(const float4*)(&hp[PLANE_H + off]);
  const float4 s2 = *(const float4*)(&hp[2 * PLANE_H + off]);
  const float4 s3 = *(const float4*)(&hp[3 * PLANE_H + off]);
  const float4 bv = (c0 < 512) ? *(const float4*)(&b0[c0])
                               : *(const float4*)(&b1[c0 - 512]);
  const float ds = dis[m];
  float4 v4;
  v4.x = fmaxf(ds * (s0.x + s1.x + s2.x + s3.x) + bv.x, 0.f);
  v4.y = fmaxf(ds * (s0.y + s1.y + s2.y + s3.y) + bv.y, 0.f);
  v4.z = fmaxf(ds * (s0.z + s1.z + s2.z + s3.z) + bv.z, 0.f);
  v4.w = fmaxf(ds * (s0.w + s1.w + s2.w + s3.w) + bv.w, 0.f);
  ushort4v h4, m4;
  split2x4(v4, h4, m4);
  *(ushort4v*)(&h2[off]) = h4;
  *(ushort4v*)(&h2[PLANE_H + off]) = m4;
}

__global__ __launch_bounds__(256) void combine_z(
    const float* __restrict__ zp, const float* __restrict__ dis,
    const float* __restrict__ b0, const float* __restrict__ b1,
    float* __restrict__ out) {
  const size_t qd = (size_t)blockIdx.x * 256 + threadIdx.x;
  const int m = (int)(qd >> 7);
  const int c0 = (int)(qd & 127) * 4;
  const size_t off = (size_t)m * 512 + c0;
  constexpr size_t PZ = (size_t)kN * 512;
  float4 acc = make_float4(0.f, 0.f, 0.f, 0.f);
#pragma unroll
  for (int s = 0; s < 8; ++s) {
    const float4 v = *(const float4*)(&zp[(size_t)s * PZ + off]);
    acc.x += v.x; acc.y += v.y; acc.z += v.z; acc.w += v.w;
  }
  const float4 bv = (c0 < 256) ? *(const float4*)(&b0[c0])
                               : *(const float4*)(&b1[c0 - 256]);
  const float ds = dis[m];
  float4 v4;
  v4.x = fmaxf(ds * acc.x + bv.x, 0.f);
  v4.y = fmaxf(ds * acc.y + bv.y, 0.f);
  v4.z = fmaxf(ds * acc.z + bv.z, 0.f);
  v4.w = fmaxf(ds * acc.w + bv.w, 0.f);
  float* dst = (c0 < 256) ? &out[(size_t)m * 256 + c0]
                          : &out[(size_t)kN * 256 + (size_t)m * 256 + (c0 - 256)];
  *(float4*)dst = v4;
}

// ============ launch ============
extern "C" void kernel_launch(void* const* d_in, const int* in_sizes, int n_in,
                              void* d_out, int out_size, void* d_ws,
                              size_t ws_size, hipStream_t stream) {
  const float* x = (const float*)d_in[0];
  const float* ne = (const float*)d_in[1];
  const float* beta = (const float*)d_in[2];
  const float* delta = (const float*)d_in[3];
  const float* epsm = (const float*)d_in[4];
  const float* Wm = (const float*)d_in[5];
  const float* bm = (const float*)d_in[6];
  const float* Ws = (const float*)d_in[7];
  const float* bs = (const float*)d_in[8];
  const float* mW0 = (const float*)d_in[9];
  const float* mb0 = (const float*)d_in[10];
  const float* mW1 = (const float*)d_in[11];
  const float* mb1 = (const float*)d_in[12];
  const float* sW0 = (const float*)d_in[13];
  const float* sb0 = (const float*)d_in[14];
  const float* sW1 = (const float*)d_in[15];
  const float* sb1 = (const float*)d_in[16];
  float* out = (float*)d_out;

  // WSR (67.1 MB) dead after adj_transpose; hp (67.1) and zp (67.1) alias it.
  char* p = (char*)d_ws;
  float* WSR = (float*)p;                     p += PLANE_NN * 4;
  unsigned short* Adj2 = (unsigned short*)p;  p += 2 * PLANE_NN * 2;
  unsigned short* x3 = (unsigned short*)p;    p += 3 * PLANE_XF * 2;  // -> V1t2
  float* XMf = (float*)p;                     p += PLANE_XF * 4;
  float* XSf = (float*)p;                     p += PLANE_XF * 4;
  unsigned short* XM2 = (unsigned short*)p;   p += 2 * PLANE_XF * 2;  // -> h2
  unsigned short* XS2 = (unsigned short*)p;   p += 2 * PLANE_XF * 2;
  unsigned short* M2 = (unsigned short*)p;    p += 2 * PLANE_XF * 2;  // -> V0t2
  unsigned short* CS2 = (unsigned short*)p;   p += 2 * PLANE_XF * 2;
  unsigned short* Wm3 = (unsigned short*)p;   p += 3 * PLANE_W * 2;
  unsigned short* Ws3 = (unsigned short*)p;   p += 3 * PLANE_W * 2;
  unsigned short* mW0t2 = (unsigned short*)p; p += 2 * PLANE_W * 2;
  unsigned short* sW0t2 = (unsigned short*)p; p += 2 * PLANE_W * 2;
  unsigned short* mW1t2 = (unsigned short*)p; p += 2 * PLANE_W1 * 2;
  unsigned short* sW1t2 = (unsigned short*)p; p += 2 * PLANE_W1 * 2;
  float* degp = (float*)p;                    p += (size_t)64 * kN * 4;
  float* rsqp = (float*)p;                    p += (size_t)32 * kN * 4;
  float* sq = (float*)p;                      p += kN * 4;
  float* csum = (float*)p;                    p += kN * 4;
  float* invn = (float*)p;                    p += kN * 4;
  float* dis = (float*)p;                     p += kN * 4;

  float* hp = WSR;   // 4 * PLANE_H floats = PLANE_NN floats exactly
  float* zp = WSR;   // 8 * kN*512 floats = PLANE_NN floats exactly
  unsigned short* V1t2 = x3;
  unsigned short* h2 = XM2;
  unsigned short* V0t2 = M2;

  const dim3 blk(256);
  const int nTri64 = (kN / 64) * (kN / 64 + 1) / 2;    // 2080 (adj)
  const int nTri128 = (kN / 128) * (kN / 128 + 1) / 2; // 528 (ws)

  prep_w<<<dim3(1024, 6), blk, 0, stream>>>(Wm, Ws, mW0, sW0, mW1, sW1, Wm3,
                                            Ws3, mW0t2, sW0t2, mW1t2, sW1t2);
  split_x<<<(kN * kF) / 256, blk, 0, stream>>>(x, x3);

  // 1) x_mean/x_std (split3, full precision) -> f32
  gemm_x<<<dim3(16, 32), blk, 0, stream>>>(x3, Wm3, Ws3, XMf, XSf, bm, bs);

  // 2) row stats + all split2 planes
  row_stats<<<kN, blk, 0, stream>>>(XMf, XSf, M2, CS2, XM2, XS2, sq, csum);

  // 3) ws_raw (128-tiles, triangle + mirror) + row-sumsq partials
  ws_mfma2<<<nTri128, blk, 0, stream>>>(M2, CS2, sq, csum, WSR, rsqp);

  // 4) invn from partials (no full-matrix re-read)
  invn_from_rsqp<<<kN / 256, blk, 0, stream>>>(rsqp, invn);

  // 5) adjacency -> Adj2 (transposed 2-plane) + deg partials. WSR dead after.
  adj_transpose<<<nTri64, blk, 0, stream>>>(WSR, invn, ne, epsm, beta, delta,
                                            Adj2, degp);
  deg_dis_kernel<<<kN / 256, blk, 0, stream>>>(degp, dis);

  // 6) V0t = (dis_i * XM@W0 | XS@W0)^T  -> split2 CT planes [1024][4096]
  gemm2ct<128, 64><<<dim3(16, 32), blk, 0, stream>>>(
      XM2, XS2, kF, PLANE_XF, mW0t2, sW0t2, kF, PLANE_W, V0t2,
      V0t2 + (size_t)512 * kN, kN, PLANE_V0, 512, kF, dis);

  // 7) h partials: AdjT @ V0t, split-K=4, XCD-swizzled (8*8*4*4 = 1024 blocks)
  gemm2k<128, 128, 8, 4, 4><<<1024, blk, 0, stream>>>(
      Adj2, kN, PLANE_NN, V0t2, kN, PLANE_V0, hp, 1024, kN, kN / 4);
  combine_h<<<(int)(PLANE_H / 4 / 256), blk, 0, stream>>>(hp, dis, mb0, sb0, h2);

  // 8) V1t = (dis_i * h@W1)^T -> split2 CT planes [512][4096]
  gemm2ct<64, 64><<<dim3(8, 64), blk, 0, stream>>>(
      h2, h2 + 512, 1024, PLANE_H, mW1t2, sW1t2, kF, PLANE_W1, V1t2,
      V1t2 + (size_t)256 * kN, kN, PLANE_V1, 256, kF, dis);

  // 9) z partials: AdjT @ V1t, split-K=8, XCD-swizzled (8*4*4*8 = 1024 blocks)
  gemm2k<128, 128, 4, 4, 8><<<1024, blk, 0, stream>>>(
      Adj2, kN, PLANE_NN, V1t2, kN, PLANE_V1, zp, 512, kN, kN / 8);
  combine_z<<<(int)((size_t)kN * 512 / 4 / 256), blk, 0, stream>>>(zp, dis, mb1,
                                                                   sb1, out);
}

// Round 11
// 682.458 us; speedup vs baseline: 1.0436x; 1.0259x over previous
//
#include <hip/hip_runtime.h>
#include <cstddef>

static constexpr int kN = 4096;
static constexpr int kF = 512;
static constexpr int kH = 256;
static constexpr float kClamp = 1e-6f;

using bf16x8 = __attribute__((ext_vector_type(8))) __bf16;
using f32x4 = __attribute__((ext_vector_type(4))) float;
using ushort8 = __attribute__((ext_vector_type(8))) unsigned short;
using ushort4v = __attribute__((ext_vector_type(4))) unsigned short;

static constexpr size_t PLANE_XF = (size_t)kN * kF;      // 2.1M
static constexpr size_t PLANE_NN = (size_t)kN * kN;      // 16.8M
static constexpr size_t PLANE_W = (size_t)512 * 512;
static constexpr size_t PLANE_W1 = (size_t)256 * 512;
static constexpr size_t PLANE_V0 = (size_t)1024 * kN;
static constexpr size_t PLANE_H = (size_t)kN * 1024;
static constexpr size_t PLANE_V1 = (size_t)512 * kN;

__device__ __forceinline__ unsigned short f2bf(float x) {
  unsigned int u = __float_as_uint(x);
  u += 0x7fffu + ((u >> 16) & 1u);
  return (unsigned short)(u >> 16);
}
__device__ __forceinline__ float bf2f(unsigned short h) {
  return __uint_as_float(((unsigned int)h) << 16);
}
__device__ __forceinline__ void split3(float x, unsigned short& h,
                                       unsigned short& m, unsigned short& l) {
  h = f2bf(x);
  const float r1 = x - bf2f(h);
  m = f2bf(r1);
  l = f2bf(r1 - bf2f(m));
}
__device__ __forceinline__ void split2(float x, unsigned short& h,
                                       unsigned short& m) {
  h = f2bf(x);
  m = f2bf(x - bf2f(h));
}
__device__ __forceinline__ void split2x4(const float4 v, ushort4v& h4,
                                         ushort4v& m4) {
  unsigned short h, m;
  split2(v.x, h, m); h4.x = h; m4.x = m;
  split2(v.y, h, m); h4.y = h; m4.y = m;
  split2(v.z, h, m); h4.z = h; m4.z = m;
  split2(v.w, h, m); h4.w = h; m4.w = m;
}

__device__ __forceinline__ bf16x8 ldfrag(const unsigned short* p) {
  ushort8 r = *(const ushort8*)p;
  return __builtin_bit_cast(bf16x8, r);
}
__device__ __forceinline__ f32x4 mfma16(bf16x8 a, bf16x8 b, f32x4 c) {
  return __builtin_amdgcn_mfma_f32_16x16x32_bf16(a, b, c, 0, 0, 0);
}
// 6-product (split3): rel err ~2^-26
__device__ __forceinline__ f32x4 mfma_split6(const bf16x8* a3, const bf16x8* b3,
                                             f32x4 acc) {
  acc = mfma16(a3[2], b3[0], acc);
  acc = mfma16(a3[0], b3[2], acc);
  acc = mfma16(a3[1], b3[1], acc);
  acc = mfma16(a3[1], b3[0], acc);
  acc = mfma16(a3[0], b3[1], acc);
  acc = mfma16(a3[0], b3[0], acc);
  return acc;
}
// XOR chunk swizzle: 16B chunk j of row r lives at chunk slot j^(r&7)
__device__ __forceinline__ int swz(int chunk, int row) {
  return (chunk ^ (row & 7)) * 8;
}

__device__ __forceinline__ void tri_map(int b, int& bi, int& bj) {
  int x = (int)((sqrtf(8.0f * (float)b + 1.0f) - 1.0f) * 0.5f);
  while ((x + 1) * (x + 2) / 2 <= b) ++x;
  while (x * (x + 1) / 2 > b) --x;
  bi = x;
  bj = b - x * (x + 1) / 2;
}

__device__ __forceinline__ float block_reduce_sum(float v, float* sbuf) {
  const int tid = threadIdx.x;
  sbuf[tid] = v;
  __syncthreads();
#pragma unroll
  for (int s = 128; s > 0; s >>= 1) {
    if (tid < s) sbuf[tid] += sbuf[tid + s];
    __syncthreads();
  }
  const float r = sbuf[0];
  __syncthreads();
  return r;
}

// ============ prep: transpose+split weights ============
__global__ __launch_bounds__(256) void prep_w(
    const float* s0, const float* s1, const float* s2, const float* s3,
    const float* s4, const float* s5, unsigned short* d0, unsigned short* d1,
    unsigned short* d2, unsigned short* d3, unsigned short* d4,
    unsigned short* d5) {
  const int seg = blockIdx.y;
  const float* src;
  unsigned short* dst;
  int N;
  bool tri;
  switch (seg) {
    case 0: src = s0; dst = d0; N = 512; tri = true; break;
    case 1: src = s1; dst = d1; N = 512; tri = true; break;
    case 2: src = s2; dst = d2; N = 512; tri = false; break;
    case 3: src = s3; dst = d3; N = 512; tri = false; break;
    case 4: src = s4; dst = d4; N = 256; tri = false; break;
    default: src = s5; dst = d5; N = 256; tri = false; break;
  }
  const int id = blockIdx.x * 256 + threadIdx.x;
  if (id >= 512 * N) return;
  const int k = id & 511;
  const int n = id >> 9;
  const float v = src[(size_t)k * N + n];
  const size_t base = (size_t)n * 512 + k;
  const size_t plane = (size_t)512 * N;
  if (tri) {
    unsigned short h, m, l;
    split3(v, h, m, l);
    dst[base] = h;
    dst[plane + base] = m;
    dst[2 * plane + base] = l;
  } else {
    unsigned short h, m;
    split2(v, h, m);
    dst[base] = h;
    dst[plane + base] = m;
  }
}

// ============ split x into 3 planes ============
__global__ __launch_bounds__(256) void split_x(const float* __restrict__ x,
                                               unsigned short* __restrict__ x3) {
  const size_t id = (size_t)blockIdx.x * 256 + threadIdx.x;
  unsigned short h, m, l;
  split3(x[id], h, m, l);
  x3[id] = h;
  x3[PLANE_XF + id] = m;
  x3[2 * PLANE_XF + id] = l;
}

// ============ GEMM-1 (split3, 6-product): x@Wm|Ws -> XMf|XSf (f32) ============
__global__ __launch_bounds__(256) void gemm_x(
    const unsigned short* __restrict__ A3, const unsigned short* __restrict__ B30,
    const unsigned short* __restrict__ B31, float* __restrict__ C0,
    float* __restrict__ C1, const float* __restrict__ bias0,
    const float* __restrict__ bias1) {
  constexpr int BM = 128, BN = 64, K = 512;
  __shared__ __align__(16) unsigned short Asl[3][BM][40];
  __shared__ __align__(16) unsigned short Bsl[3][BN][40];
  const int tid = threadIdx.x;
  const int lane = tid & 63;
  const int wave = tid >> 6;
  const int wm = wave >> 1, wn = wave & 1;
  const int m0 = blockIdx.y * BM;
  const int n0 = blockIdx.x * BN;
  const bool str1 = (n0 >= 512);
  const int nloc = str1 ? (n0 - 512) : n0;
  const unsigned short* Bb = str1 ? B31 : B30;
  const float* bias = str1 ? bias1 : bias0;
  float* C = str1 ? C1 : C0;
  const int rl = lane & 15;
  const int kq = (lane >> 4) * 8;
  const int q = lane >> 4;

  f32x4 acc[4][2];
#pragma unroll
  for (int i = 0; i < 4; ++i)
#pragma unroll
    for (int j = 0; j < 2; ++j) acc[i][j] = (f32x4){0.f, 0.f, 0.f, 0.f};

  for (int k0 = 0; k0 < K; k0 += 32) {
#pragma unroll
    for (int it = 0; it < 6; ++it) {
      const int c = tid + it * 256;
      const int plane = c / (BM * 4);
      const int rem = c % (BM * 4);
      const int row = rem >> 2;
      const int kc = (rem & 3) * 8;
      const ushort8 v = *(const ushort8*)(&A3[(size_t)plane * PLANE_XF +
                                              (size_t)(m0 + row) * K + k0 + kc]);
      *(ushort8*)(&Asl[plane][row][kc]) = v;
    }
#pragma unroll
    for (int it = 0; it < 3; ++it) {
      const int c = tid + it * 256;
      const int plane = c / (BN * 4);
      const int rem = c % (BN * 4);
      const int row = rem >> 2;
      const int kc = (rem & 3) * 8;
      const ushort8 v = *(const ushort8*)(&Bb[(size_t)plane * PLANE_W +
                                              (size_t)(nloc + row) * K + k0 + kc]);
      *(ushort8*)(&Bsl[plane][row][kc]) = v;
    }
    __syncthreads();
    bf16x8 af[4][3], bfr[2][3];
#pragma unroll
    for (int mt = 0; mt < 4; ++mt)
#pragma unroll
      for (int t = 0; t < 3; ++t)
        af[mt][t] = ldfrag(&Asl[t][wm * 64 + mt * 16 + rl][kq]);
#pragma unroll
    for (int nt = 0; nt < 2; ++nt)
#pragma unroll
      for (int t = 0; t < 3; ++t)
        bfr[nt][t] = ldfrag(&Bsl[t][wn * 32 + nt * 16 + rl][kq]);
#pragma unroll
    for (int mt = 0; mt < 4; ++mt)
#pragma unroll
      for (int nt = 0; nt < 2; ++nt)
        acc[mt][nt] = mfma_split6(af[mt], bfr[nt], acc[mt][nt]);
    __syncthreads();
  }
#pragma unroll
  for (int mt = 0; mt < 4; ++mt)
#pragma unroll
    for (int nt = 0; nt < 2; ++nt) {
      const int col = nloc + wn * 32 + nt * 16 + rl;
      const int row0 = m0 + wm * 64 + mt * 16 + q * 4;
      const float bv = bias[col];
#pragma unroll
      for (int r = 0; r < 4; ++r)
        C[(size_t)(row0 + r) * 512 + col] = acc[mt][nt][r] + bv;
    }
}

// ============ split2 3-product GEMM, CT-split2 output (small GEMMs) ============
// Swizzled LDS rows: 64 ushorts/row (2 planes x 32k), chunk j at j^(r&7).
template <int BM, int BN>
__global__ __launch_bounds__(256) void gemm2ct(
    const unsigned short* __restrict__ A0, const unsigned short* __restrict__ A1,
    int lda, size_t planeA, const unsigned short* __restrict__ B0,
    const unsigned short* __restrict__ B1, int ldb, size_t planeB,
    unsigned short* __restrict__ Cs0, unsigned short* __restrict__ Cs1, int ldc,
    size_t planeC, int N1, int K, const float* __restrict__ rowScale) {
  __shared__ __align__(16) unsigned short Asl[BM][64];
  __shared__ __align__(16) unsigned short Bsl[BN][64];
  const int tid = threadIdx.x;
  const int lane = tid & 63;
  const int wave = tid >> 6;
  const int wm = wave >> 1, wn = wave & 1;
  const int m0 = blockIdx.y * BM;
  const int n0 = blockIdx.x * BN;
  const bool str1 = (n0 >= N1);
  const int nloc = str1 ? (n0 - N1) : n0;
  const unsigned short* Ab = str1 ? A1 : A0;
  const unsigned short* Bb = str1 ? B1 : B0;
  const int rl = lane & 15;
  const int q = lane >> 4;
  constexpr int MT = BM / 32;
  constexpr int NT = BN / 32;

  f32x4 acc[MT][NT];
#pragma unroll
  for (int i = 0; i < MT; ++i)
#pragma unroll
    for (int j = 0; j < NT; ++j) acc[i][j] = (f32x4){0.f, 0.f, 0.f, 0.f};

  for (int k0 = 0; k0 < K; k0 += 32) {
    constexpr int AIT = (2 * BM * 4) / 256;
#pragma unroll
    for (int it = 0; it < AIT; ++it) {
      const int c = tid + it * 256;
      const int plane = c / (BM * 4);
      const int rem = c % (BM * 4);
      const int row = rem >> 2;
      const int kcc = rem & 3;
      const ushort8 v = *(const ushort8*)(&Ab[(size_t)plane * planeA +
                                              (size_t)(m0 + row) * lda + k0 +
                                              kcc * 8]);
      *(ushort8*)(&Asl[row][swz(plane * 4 + kcc, row)]) = v;
    }
    constexpr int BIT = (2 * BN * 4) / 256;
#pragma unroll
    for (int it = 0; it < BIT; ++it) {
      const int c = tid + it * 256;
      const int plane = c / (BN * 4);
      const int rem = c % (BN * 4);
      const int row = rem >> 2;
      const int kcc = rem & 3;
      const ushort8 v = *(const ushort8*)(&Bb[(size_t)plane * planeB +
                                              (size_t)(nloc + row) * ldb + k0 +
                                              kcc * 8]);
      *(ushort8*)(&Bsl[row][swz(plane * 4 + kcc, row)]) = v;
    }
    __syncthreads();
    bf16x8 af[MT][2];
#pragma unroll
    for (int mt = 0; mt < MT; ++mt) {
      const int row = wm * (BM / 2) + mt * 16 + rl;
#pragma unroll
      for (int t = 0; t < 2; ++t)
        af[mt][t] = ldfrag(&Asl[row][swz(t * 4 + q, row)]);
    }
#pragma unroll
    for (int nt = 0; nt < NT; ++nt) {
      const int row = wn * (BN / 2) + nt * 16 + rl;
      const bf16x8 b0 = ldfrag(&Bsl[row][swz(q, row)]);
      const bf16x8 b1 = ldfrag(&Bsl[row][swz(4 + q, row)]);
#pragma unroll
      for (int mt = 0; mt < MT; ++mt) {
        acc[mt][nt] = mfma16(af[mt][1], b0, acc[mt][nt]);
        acc[mt][nt] = mfma16(af[mt][0], b1, acc[mt][nt]);
        acc[mt][nt] = mfma16(af[mt][0], b0, acc[mt][nt]);
      }
    }
    __syncthreads();
  }

#pragma unroll
  for (int mt = 0; mt < MT; ++mt) {
#pragma unroll
    for (int nt = 0; nt < NT; ++nt) {
      const int colL = nloc + wn * (BN / 2) + nt * 16 + rl;
      const int row0 = m0 + wm * (BM / 2) + mt * 16 + q * 4;
      float4 v4;
      float* vp = &v4.x;
#pragma unroll
      for (int r = 0; r < 4; ++r) {
        float v = acc[mt][nt][r];
        if (rowScale) v *= rowScale[row0 + r];
        vp[r] = v;
      }
      unsigned short* C = str1 ? Cs1 : Cs0;
      ushort4v h4, m4;
      split2x4(v4, h4, m4);
      const size_t base = (size_t)colL * ldc + row0;
      *(ushort4v*)(&C[base]) = h4;
      *(ushort4v*)(&C[planeC + base]) = m4;
    }
  }
}

// ============ split2 3-product GEMM, split-K partials, XCD-swizzled ============
// 32 KiB swizzled LDS -> 4+ blocks/CU.
template <int BM, int BN, int GX, int GYP, int GZ>
__global__ __launch_bounds__(256) void gemm2k(
    const unsigned short* __restrict__ A, int lda, size_t planeA,
    const unsigned short* __restrict__ B, int ldb, size_t planeB,
    float* __restrict__ Cp, int ldc, int Mtot, int Ksl) {
  __shared__ __align__(16) unsigned short Asl[BM][64];
  __shared__ __align__(16) unsigned short Bsl[BN][64];
  const int lin = blockIdx.x;
  const int xcd = lin & 7;
  const int s = lin >> 3;
  constexpr int per = GX * GYP;
  const int z = s / per;
  const int r = s - z * per;
  const int bx = r % GX;
  const int by = xcd * GYP + r / GX;
  const int m0 = by * BM;
  const int n0 = bx * BN;
  const int kOff = z * Ksl;

  const int tid = threadIdx.x;
  const int lane = tid & 63;
  const int wave = tid >> 6;
  const int wm = wave >> 1, wn = wave & 1;
  const int rl = lane & 15;
  const int q = lane >> 4;
  constexpr int MT = BM / 32;
  constexpr int NT = BN / 32;

  f32x4 acc[MT][NT];
#pragma unroll
  for (int i = 0; i < MT; ++i)
#pragma unroll
    for (int j = 0; j < NT; ++j) acc[i][j] = (f32x4){0.f, 0.f, 0.f, 0.f};

  for (int k0 = 0; k0 < Ksl; k0 += 32) {
    constexpr int AIT = (2 * BM * 4) / 256;
#pragma unroll
    for (int it = 0; it < AIT; ++it) {
      const int c = tid + it * 256;
      const int plane = c / (BM * 4);
      const int rem = c % (BM * 4);
      const int row = rem >> 2;
      const int kcc = rem & 3;
      const ushort8 v = *(const ushort8*)(&A[(size_t)plane * planeA +
                                             (size_t)(m0 + row) * lda + kOff +
                                             k0 + kcc * 8]);
      *(ushort8*)(&Asl[row][swz(plane * 4 + kcc, row)]) = v;
    }
    constexpr int BIT = (2 * BN * 4) / 256;
#pragma unroll
    for (int it = 0; it < BIT; ++it) {
      const int c = tid + it * 256;
      const int plane = c / (BN * 4);
      const int rem = c % (BN * 4);
      const int row = rem >> 2;
      const int kcc = rem & 3;
      const ushort8 v = *(const ushort8*)(&B[(size_t)plane * planeB +
                                             (size_t)(n0 + row) * ldb + kOff +
                                             k0 + kcc * 8]);
      *(ushort8*)(&Bsl[row][swz(plane * 4 + kcc, row)]) = v;
    }
    __syncthreads();
    bf16x8 af[MT][2];
#pragma unroll
    for (int mt = 0; mt < MT; ++mt) {
      const int row = wm * (BM / 2) + mt * 16 + rl;
#pragma unroll
      for (int t = 0; t < 2; ++t)
        af[mt][t] = ldfrag(&Asl[row][swz(t * 4 + q, row)]);
    }
#pragma unroll
    for (int nt = 0; nt < NT; ++nt) {
      const int row = wn * (BN / 2) + nt * 16 + rl;
      const bf16x8 b0 = ldfrag(&Bsl[row][swz(q, row)]);
      const bf16x8 b1 = ldfrag(&Bsl[row][swz(4 + q, row)]);
#pragma unroll
      for (int mt = 0; mt < MT; ++mt) {
        acc[mt][nt] = mfma16(af[mt][1], b0, acc[mt][nt]);
        acc[mt][nt] = mfma16(af[mt][0], b1, acc[mt][nt]);
        acc[mt][nt] = mfma16(af[mt][0], b0, acc[mt][nt]);
      }
    }
    __syncthreads();
  }

  const size_t zoff = (size_t)z * (size_t)Mtot * (size_t)ldc;
#pragma unroll
  for (int mt = 0; mt < MT; ++mt) {
#pragma unroll
    for (int nt = 0; nt < NT; ++nt) {
      const int colL = n0 + wn * (BN / 2) + nt * 16 + rl;
      const int row0 = m0 + wm * (BM / 2) + mt * 16 + q * 4;
#pragma unroll
      for (int r = 0; r < 4; ++r)
        Cp[zoff + (size_t)(row0 + r) * ldc + colL] = acc[mt][nt][r];
    }
  }
}

// ============ row stats: XMf/XSf f32 -> M2/CS2/XM2/XS2 planes ============
__global__ __launch_bounds__(256) void row_stats(
    const float* __restrict__ XMf, const float* __restrict__ XSf,
    unsigned short* __restrict__ M2, unsigned short* __restrict__ CS2,
    unsigned short* __restrict__ XM2, unsigned short* __restrict__ XS2,
    float* __restrict__ sq, float* __restrict__ csum) {
  __shared__ float sbuf[256];
  const int i = blockIdx.x;
  const int tid = threadIdx.x;
  const size_t base = (size_t)i * kF;
  const size_t i0 = base + tid, i1 = base + tid + 256;
  const float x0 = XMf[i0], x1 = XMf[i1];
  {
    unsigned short h, m;
    split2(x0, h, m);
    XM2[i0] = h; XM2[PLANE_XF + i0] = m;
    split2(x1, h, m);
    XM2[i1] = h; XM2[PLANE_XF + i1] = m;
  }
  const float nrm = block_reduce_sum(x0 * x0 + x1 * x1, sbuf);
  const float inv = 1.0f / fmaxf(sqrtf(nrm), 1e-12f);
  const float m0 = x0 * inv, m1 = x1 * inv;
  {
    unsigned short h, m;
    split2(m0, h, m);
    M2[i0] = h; M2[PLANE_XF + i0] = m;
    split2(m1, h, m);
    M2[i1] = h; M2[PLANE_XF + i1] = m;
  }
  const float s2 = block_reduce_sum(m0 * m0 + m1 * m1, sbuf);
  if (tid == 0) sq[i] = s2;

  const float y0 = XSf[i0], y1 = XSf[i1];
  {
    unsigned short h, m;
    split2(y0, h, m);
    XS2[i0] = h; XS2[PLANE_XF + i0] = m;
    split2(y1, h, m);
    XS2[i1] = h; XS2[PLANE_XF + i1] = m;
  }
  const float e0 = expf(y0), e1 = expf(y1);
  const float nrm2 = block_reduce_sum(e0 * e0 + e1 * e1, sbuf);
  const float inv2 = 1.0f / fmaxf(sqrtf(nrm2), 1e-12f);
  const float c0 = e0 * inv2, c1 = e1 * inv2;
  const float sc = block_reduce_sum(c0 + c1, sbuf);
  if (tid == 0) csum[i] = sc;
  {
    unsigned short h, m;
    split2(sqrtf(c0), h, m);
    CS2[i0] = h; CS2[PLANE_XF + i0] = m;
    split2(sqrtf(c1), h, m);
    CS2[i1] = h; CS2[PLANE_XF + i1] = m;
  }
}

// ============ symmetric dual NT-GEMM, 128x128 tiles, 3-prod split2 ============
// Swizzled LDS rows (64 ushorts, chunk j at j^(r&7)): exactly 64 KiB total.
// Emits row/col sumsq partials (rsqp).
__global__ __launch_bounds__(256, 2) void ws_mfma2(
    const unsigned short* __restrict__ M2, const unsigned short* __restrict__ CS2,
    const float* __restrict__ sq, const float* __restrict__ csum,
    float* __restrict__ WSR, float* __restrict__ rsqp) {
  __shared__ __align__(16) unsigned short S[4][128][64];  // 65536 B exactly
  int bi, bj;
  tri_map(blockIdx.x, bi, bj);  // 32x32 tile grid, bi >= bj
  const int i0 = bi * 128, j0 = bj * 128;
  const int tid = threadIdx.x;
  const int lane = tid & 63;
  const int wave = tid >> 6;
  const int wm = wave >> 1, wn = wave & 1;
  const int rl = lane & 15;
  const int q = lane >> 4;

  f32x4 aM[4][4], aC[4][4];
#pragma unroll
  for (int i = 0; i < 4; ++i)
#pragma unroll
    for (int j = 0; j < 4; ++j) {
      aM[i][j] = (f32x4){0.f, 0.f, 0.f, 0.f};
      aC[i][j] = (f32x4){0.f, 0.f, 0.f, 0.f};
    }

  for (int k0 = 0; k0 < kF; k0 += 32) {
    // stage 4 ops x 2 planes x 128 rows x 4 chunks  (4096 ushort8 slots)
#pragma unroll
    for (int it = 0; it < 16; ++it) {
      const int c = tid + it * 256;
      const int op = c >> 10;
      const int rem = c & 1023;
      const int plane = rem >> 9;
      const int r2 = rem & 511;
      const int row = r2 >> 2;
      const int kcc = r2 & 3;
      const unsigned short* mat = (op & 1) ? CS2 : M2;
      const int rowoff = (op < 2) ? i0 : j0;
      const ushort8 v = *(const ushort8*)(&mat[(size_t)plane * PLANE_XF +
                                               (size_t)(rowoff + row) * kF + k0 +
                                               kcc * 8]);
      *(ushort8*)(&S[op][row][swz(plane * 4 + kcc, row)]) = v;
    }
    __syncthreads();
    {
      bf16x8 a_[4][2], b_[4][2];
#pragma unroll
      for (int mt = 0; mt < 4; ++mt) {
        const int row = wm * 64 + mt * 16 + rl;
#pragma unroll
        for (int t = 0; t < 2; ++t)
          a_[mt][t] = ldfrag(&S[0][row][swz(t * 4 + q, row)]);
      }
#pragma unroll
      for (int nt = 0; nt < 4; ++nt) {
        const int row = wn * 64 + nt * 16 + rl;
#pragma unroll
        for (int t = 0; t < 2; ++t)
          b_[nt][t] = ldfrag(&S[2][row][swz(t * 4 + q, row)]);
      }
#pragma unroll
      for (int mt = 0; mt < 4; ++mt)
#pragma unroll
        for (int nt = 0; nt < 4; ++nt) {
          aM[mt][nt] = mfma16(a_[mt][1], b_[nt][0], aM[mt][nt]);
          aM[mt][nt] = mfma16(a_[mt][0], b_[nt][1], aM[mt][nt]);
          aM[mt][nt] = mfma16(a_[mt][0], b_[nt][0], aM[mt][nt]);
        }
    }
    {
      bf16x8 a_[4][2], b_[4][2];
#pragma unroll
      for (int mt = 0; mt < 4; ++mt) {
        const int row = wm * 64 + mt * 16 + rl;
#pragma unroll
        for (int t = 0; t < 2; ++t)
          a_[mt][t] = ldfrag(&S[1][row][swz(t * 4 + q, row)]);
      }
#pragma unroll
      for (int nt = 0; nt < 4; ++nt) {
        const int row = wn * 64 + nt * 16 + rl;
#pragma unroll
        for (int t = 0; t < 2; ++t)
          b_[nt][t] = ldfrag(&S[3][row][swz(t * 4 + q, row)]);
      }
#pragma unroll
      for (int mt = 0; mt < 4; ++mt)
#pragma unroll
        for (int nt = 0; nt < 4; ++nt) {
          aC[mt][nt] = mfma16(a_[mt][1], b_[nt][0], aC[mt][nt]);
          aC[mt][nt] = mfma16(a_[mt][0], b_[nt][1], aC[mt][nt]);
          aC[mt][nt] = mfma16(a_[mt][0], b_[nt][0], aC[mt][nt]);
        }
    }
    __syncthreads();
  }

  // epilogue: reuse S memory for row/col sum-of-squares reduction
  float* rs_ = (float*)&S[0][0][0];  // [128] row partials (direct tile)
  float* cs_ = rs_ + 128;            // [128] col partials (mirror rows)
  if (tid < 256) rs_[tid] = 0.f;
  __syncthreads();

  float rowacc[4][4];
  float colacc[4];
#pragma unroll
  for (int i = 0; i < 4; ++i) {
    colacc[i] = 0.f;
#pragma unroll
    for (int j = 0; j < 4; ++j) rowacc[i][j] = 0.f;
  }

#pragma unroll
  for (int mt = 0; mt < 4; ++mt) {
#pragma unroll
    for (int nt = 0; nt < 4; ++nt) {
      const int j = j0 + wn * 64 + nt * 16 + rl;
      const int ib = i0 + wm * 64 + mt * 16 + q * 4;
      const float sqj = sq[j], csj = csum[j];
      float4 vv;
      float* vp = &vv.x;
#pragma unroll
      for (int r = 0; r < 4; ++r) {
        const int i = ib + r;
        const float d2 = fmaxf(sq[i] + sqj - 2.0f * aM[mt][nt][r], 0.0f);
        const float res = d2 + csum[i] + csj - 2.0f * aC[mt][nt][r];
        const float v = expf(-res);
        vp[r] = v;
        WSR[(size_t)i * kN + j] = v;
        rowacc[mt][r] += v * v;
        colacc[nt] += v * v;
      }
      if (bi != bj) *(float4*)(&WSR[(size_t)j * kN + ib]) = vv;
    }
  }
#pragma unroll
  for (int mt = 0; mt < 4; ++mt)
#pragma unroll
    for (int r = 0; r < 4; ++r)
      atomicAdd(&rs_[wm * 64 + mt * 16 + q * 4 + r], rowacc[mt][r]);
#pragma unroll
  for (int nt = 0; nt < 4; ++nt)
    atomicAdd(&cs_[wn * 64 + nt * 16 + rl], colacc[nt]);
  __syncthreads();
  if (tid < 128) {
    rsqp[(size_t)bj * kN + i0 + tid] = rs_[tid];
    if (bi != bj) rsqp[(size_t)bi * kN + j0 + tid] = cs_[tid];
  }
}

// ============ invn from rsqp slabs ============
__global__ __launch_bounds__(256) void invn_from_rsqp(
    const float* __restrict__ rsqp, float* __restrict__ invn) {
  const int i = blockIdx.x * 256 + threadIdx.x;
  float s = 0.0f;
#pragma unroll
  for (int c = 0; c < 32; ++c) s += rsqp[(size_t)c * kN + i];
  invn[i] = 1.0f / fmaxf(sqrtf(s), 1e-12f);
}

// ============ adjacency transform + transposed 2-plane split + deg ============
__device__ __forceinline__ float adj_val(float w, float inv, float nev, float ev,
                                         float b, float d, bool diag) {
  float t = (1.0f - b) * (w * inv) + b * nev;
  t = fminf(fmaxf(t, kClamp), 1.0f - kClamp);
  float L = logf(t / (1.0f - t));
  const float e = fminf(fmaxf(ev, kClamp), 1.0f - kClamp);
  L += logf(e / (1.0f - e));
  const float s = 1.0f / (1.0f + expf(-L));
  float v = (s > d) ? s : 0.0f;
  if (diag) v = (v > 0.0f) ? v : 1.0f;
  return v;
}

__global__ __launch_bounds__(256) void adj_transpose(
    const float* __restrict__ WSR, const float* __restrict__ invn,
    const float* __restrict__ ne, const float* __restrict__ epsm,
    const float* __restrict__ beta_p, const float* __restrict__ delta_p,
    unsigned short* __restrict__ Adj2, float* __restrict__ degp) {
  __shared__ float T0[64][65];
  __shared__ float T1[64][65];
  const float b = beta_p[0];
  const float d = delta_p[0];
  int bi, bj;
  tri_map(blockIdx.x, bi, bj);
  const int i0 = bi * 64, j0 = bj * 64;
  const int tid = threadIdx.x;
  const int rlq = tid >> 4;
  const int cq = (tid & 15) * 4;
#pragma unroll
  for (int p = 0; p < 4; ++p) {
    const int ii = p * 16 + rlq;
    {
      const size_t off = (size_t)(i0 + ii) * kN + j0 + cq;
      const float4 w4 = *(const float4*)(&WSR[off]);
      const float4 n4 = *(const float4*)(&ne[off]);
      const float4 e4 = *(const float4*)(&epsm[off]);
      const float inv = invn[i0 + ii];
      const float wv[4] = {w4.x, w4.y, w4.z, w4.w};
      const float nv[4] = {n4.x, n4.y, n4.z, n4.w};
      const float ev[4] = {e4.x, e4.y, e4.z, e4.w};
#pragma unroll
      for (int u = 0; u < 4; ++u)
        T0[ii][cq + u] =
            adj_val(wv[u], inv, nv[u], ev[u], b, d, (i0 + ii) == (j0 + cq + u));
    }
    if (bi != bj) {
      const size_t off = (size_t)(j0 + ii) * kN + i0 + cq;
      const float4 w4 = *(const float4*)(&WSR[off]);
      const float4 n4 = *(const float4*)(&ne[off]);
      const float4 e4 = *(const float4*)(&epsm[off]);
      const float inv = invn[j0 + ii];
      const float wv[4] = {w4.x, w4.y, w4.z, w4.w};
      const float nv[4] = {n4.x, n4.y, n4.z, n4.w};
      const float ev[4] = {e4.x, e4.y, e4.z, e4.w};
#pragma unroll
      for (int u = 0; u < 4; ++u)
        T1[ii][cq + u] = adj_val(wv[u], inv, nv[u], ev[u], b, d, false);
    }
  }
  __syncthreads();
#pragma unroll
  for (int p = 0; p < 4; ++p) {
    const int jj = p * 16 + rlq;
    {
      const float4 v4 = make_float4(T0[cq + 0][jj], T0[cq + 1][jj],
                                    T0[cq + 2][jj], T0[cq + 3][jj]);
      ushort4v h4, m4;
      split2x4(v4, h4, m4);
      const size_t base = (size_t)(j0 + jj) * kN + i0 + cq;
      *(ushort4v*)(&Adj2[base]) = h4;
      *(ushort4v*)(&Adj2[PLANE_NN + base]) = m4;
    }
    if (bi != bj) {
      const float4 v4 = make_float4(T1[cq + 0][jj], T1[cq + 1][jj],
                                    T1[cq + 2][jj], T1[cq + 3][jj]);
      ushort4v h4, m4;
      split2x4(v4, h4, m4);
      const size_t base = (size_t)(i0 + jj) * kN + j0 + cq;
      *(ushort4v*)(&Adj2[base]) = h4;
      *(ushort4v*)(&Adj2[PLANE_NN + base]) = m4;
    }
  }
  if (tid < 64) {
    float s = 0.0f;
#pragma unroll 8
    for (int ii = 0; ii < 64; ++ii) s += T0[ii][tid];
    degp[(size_t)bi * kN + j0 + tid] = s;
    if (bi != bj) {
      float s1 = 0.0f;
#pragma unroll 8
      for (int ii = 0; ii < 64; ++ii) s1 += T1[ii][tid];
      degp[(size_t)bj * kN + i0 + tid] = s1;
    }
  }
}

__global__ __launch_bounds__(256) void deg_dis_kernel(
    const float* __restrict__ degp, float* __restrict__ dis) {
  const int j = blockIdx.x * 256 + threadIdx.x;
  float s = 0.0f;
#pragma unroll
  for (int c = 0; c < 64; ++c) s += degp[(size_t)c * kN + j];
  dis[j] = (s > 0.0f) ? (1.0f / sqrtf(s)) : 0.0f;
}

// ============ split-K combines ============
__global__ __launch_bounds__(256) void combine_h(
    const float* __restrict__ hp, const float* __restrict__ dis,
    const float* __restrict__ b0, const float* __restrict__ b1,
    unsigned short* __restrict__ h2) {
  const size_t qd = (size_t)blockIdx.x * 256 + threadIdx.x;
  const int m = (int)(qd >> 8);
  const int c0 = (int)(qd & 255) * 4;
  const size_t off = (size_t)m * 1024 + c0;
  const float4 s0 = *(const float4*)(&hp[off]);
  const float4 s1 = *(const float4*)(&hp[PLANE_H + off]);
  const float4 s2 = *(const float4*)(&hp[2 * PLANE_H + off]);
  const float4 s3 = *(const float4*)(&hp[3 * PLANE_H + off]);
  const float4 bv = (c0 < 512) ? *(const float4*)(&b0[c0])
                               : *(const float4*)(&b1[c0 - 512]);
  const float ds = dis[m];
  float4 v4;
  v4.x = fmaxf(ds * (s0.x + s1.x + s2.x + s3.x) + bv.x, 0.f);
  v4.y = fmaxf(ds * (s0.y + s1.y + s2.y + s3.y) + bv.y, 0.f);
  v4.z = fmaxf(ds * (s0.z + s1.z + s2.z + s3.z) + bv.z, 0.f);
  v4.w = fmaxf(ds * (s0.w + s1.w + s2.w + s3.w) + bv.w, 0.f);
  ushort4v h4, m4;
  split2x4(v4, h4, m4);
  *(ushort4v*)(&h2[off]) = h4;
  *(ushort4v*)(&h2[PLANE_H + off]) = m4;
}

__global__ __launch_bounds__(256) void combine_z(
    const float* __restrict__ zp, const float* __restrict__ dis,
    const float* __restrict__ b0, const float* __restrict__ b1,
    float* __restrict__ out) {
  const size_t qd = (size_t)blockIdx.x * 256 + threadIdx.x;
  const int m = (int)(qd >> 7);
  const int c0 = (int)(qd & 127) * 4;
  const size_t off = (size_t)m * 512 + c0;
  constexpr size_t PZ = (size_t)kN * 512;
  float4 acc = make_float4(0.f, 0.f, 0.f, 0.f);
#pragma unroll
  for (int s = 0; s < 8; ++s) {
    const float4 v = *(const float4*)(&zp[(size_t)s * PZ + off]);
    acc.x += v.x; acc.y += v.y; acc.z += v.z; acc.w += v.w;
  }
  const float4 bv = (c0 < 256) ? *(const float4*)(&b0[c0])
                               : *(const float4*)(&b1[c0 - 256]);
  const float ds = dis[m];
  float4 v4;
  v4.x = fmaxf(ds * acc.x + bv.x, 0.f);
  v4.y = fmaxf(ds * acc.y + bv.y, 0.f);
  v4.z = fmaxf(ds * acc.z + bv.z, 0.f);
  v4.w = fmaxf(ds * acc.w + bv.w, 0.f);
  float* dst = (c0 < 256) ? &out[(size_t)m * 256 + c0]
                          : &out[(size_t)kN * 256 + (size_t)m * 256 + (c0 - 256)];
  *(float4*)dst = v4;
}

// ============ launch ============
extern "C" void kernel_launch(void* const* d_in, const int* in_sizes, int n_in,
                              void* d_out, int out_size, void* d_ws,
                              size_t ws_size, hipStream_t stream) {
  const float* x = (const float*)d_in[0];
  const float* ne = (const float*)d_in[1];
  const float* beta = (const float*)d_in[2];
  const float* delta = (const float*)d_in[3];
  const float* epsm = (const float*)d_in[4];
  const float* Wm = (const float*)d_in[5];
  const float* bm = (const float*)d_in[6];
  const float* Ws = (const float*)d_in[7];
  const float* bs = (const float*)d_in[8];
  const float* mW0 = (const float*)d_in[9];
  const float* mb0 = (const float*)d_in[10];
  const float* mW1 = (const float*)d_in[11];
  const float* mb1 = (const float*)d_in[12];
  const float* sW0 = (const float*)d_in[13];
  const float* sb0 = (const float*)d_in[14];
  const float* sW1 = (const float*)d_in[15];
  const float* sb1 = (const float*)d_in[16];
  float* out = (float*)d_out;

  // WSR (67.1 MB) dead after adj_transpose; hp (67.1) and zp (67.1) alias it.
  char* p = (char*)d_ws;
  float* WSR = (float*)p;                     p += PLANE_NN * 4;
  unsigned short* Adj2 = (unsigned short*)p;  p += 2 * PLANE_NN * 2;
  unsigned short* x3 = (unsigned short*)p;    p += 3 * PLANE_XF * 2;  // -> V1t2
  float* XMf = (float*)p;                     p += PLANE_XF * 4;
  float* XSf = (float*)p;                     p += PLANE_XF * 4;
  unsigned short* XM2 = (unsigned short*)p;   p += 2 * PLANE_XF * 2;  // -> h2
  unsigned short* XS2 = (unsigned short*)p;   p += 2 * PLANE_XF * 2;
  unsigned short* M2 = (unsigned short*)p;    p += 2 * PLANE_XF * 2;  // -> V0t2
  unsigned short* CS2 = (unsigned short*)p;   p += 2 * PLANE_XF * 2;
  unsigned short* Wm3 = (unsigned short*)p;   p += 3 * PLANE_W * 2;
  unsigned short* Ws3 = (unsigned short*)p;   p += 3 * PLANE_W * 2;
  unsigned short* mW0t2 = (unsigned short*)p; p += 2 * PLANE_W * 2;
  unsigned short* sW0t2 = (unsigned short*)p; p += 2 * PLANE_W * 2;
  unsigned short* mW1t2 = (unsigned short*)p; p += 2 * PLANE_W1 * 2;
  unsigned short* sW1t2 = (unsigned short*)p; p += 2 * PLANE_W1 * 2;
  float* degp = (float*)p;                    p += (size_t)64 * kN * 4;
  float* rsqp = (float*)p;                    p += (size_t)32 * kN * 4;
  float* sq = (float*)p;                      p += kN * 4;
  float* csum = (float*)p;                    p += kN * 4;
  float* invn = (float*)p;                    p += kN * 4;
  float* dis = (float*)p;                     p += kN * 4;

  float* hp = WSR;   // 4 * PLANE_H floats = PLANE_NN floats exactly
  float* zp = WSR;   // 8 * kN*512 floats = PLANE_NN floats exactly
  unsigned short* V1t2 = x3;
  unsigned short* h2 = XM2;
  unsigned short* V0t2 = M2;

  const dim3 blk(256);
  const int nTri64 = (kN / 64) * (kN / 64 + 1) / 2;    // 2080 (adj)
  const int nTri128 = (kN / 128) * (kN / 128 + 1) / 2; // 528 (ws)

  prep_w<<<dim3(1024, 6), blk, 0, stream>>>(Wm, Ws, mW0, sW0, mW1, sW1, Wm3,
                                            Ws3, mW0t2, sW0t2, mW1t2, sW1t2);
  split_x<<<(kN * kF) / 256, blk, 0, stream>>>(x, x3);

  // 1) x_mean/x_std (split3, full precision) -> f32
  gemm_x<<<dim3(16, 32), blk, 0, stream>>>(x3, Wm3, Ws3, XMf, XSf, bm, bs);

  // 2) row stats + all split2 planes
  row_stats<<<kN, blk, 0, stream>>>(XMf, XSf, M2, CS2, XM2, XS2, sq, csum);

  // 3) ws_raw (128-tiles, triangle + mirror) + row-sumsq partials
  ws_mfma2<<<nTri128, blk, 0, stream>>>(M2, CS2, sq, csum, WSR, rsqp);

  // 4) invn from partials (no full-matrix re-read)
  invn_from_rsqp<<<kN / 256, blk, 0, stream>>>(rsqp, invn);

  // 5) adjacency -> Adj2 (transposed 2-plane) + deg partials. WSR dead after.
  adj_transpose<<<nTri64, blk, 0, stream>>>(WSR, invn, ne, epsm, beta, delta,
                                            Adj2, degp);
  deg_dis_kernel<<<kN / 256, blk, 0, stream>>>(degp, dis);

  // 6) V0t = (dis_i * XM@W0 | XS@W0)^T  -> split2 CT planes [1024][4096]
  gemm2ct<128, 64><<<dim3(16, 32), blk, 0, stream>>>(
      XM2, XS2, kF, PLANE_XF, mW0t2, sW0t2, kF, PLANE_W, V0t2,
      V0t2 + (size_t)512 * kN, kN, PLANE_V0, 512, kF, dis);

  // 7) h partials: AdjT @ V0t, split-K=4, XCD-swizzled (8*8*4*4 = 1024 blocks)
  gemm2k<128, 128, 8, 4, 4><<<1024, blk, 0, stream>>>(
      Adj2, kN, PLANE_NN, V0t2, kN, PLANE_V0, hp, 1024, kN, kN / 4);
  combine_h<<<(int)(PLANE_H / 4 / 256), blk, 0, stream>>>(hp, dis, mb0, sb0, h2);

  // 8) V1t = (dis_i * h@W1)^T -> split2 CT planes [512][4096]
  gemm2ct<64, 64><<<dim3(8, 64), blk, 0, stream>>>(
      h2, h2 + 512, 1024, PLANE_H, mW1t2, sW1t2, kF, PLANE_W1, V1t2,
      V1t2 + (size_t)256 * kN, kN, PLANE_V1, 256, kF, dis);

  // 9) z partials: AdjT @ V1t, split-K=8, XCD-swizzled (8*4*4*8 = 1024 blocks)
  gemm2k<128, 128, 4, 4, 8><<<1024, blk, 0, stream>>>(
      Adj2, kN, PLANE_NN, V1t2, kN, PLANE_V1, zp, 512, kN, kN / 8);
  combine_z<<<(int)((size_t)kN * 512 / 4 / 256), blk, 0, stream>>>(zp, dis, mb1,
                                                                   sb1, out);
}